// Round 2
// baseline (865.776 us; speedup 1.0000x reference)
//
#include <hip/hip_runtime.h>
#include <hip/hip_fp16.h>

#define SQ   4096
#define DIMM 2048
#define QKVN 4096   // 2048 q | 1024 k | 1024 v

typedef unsigned short u16;
typedef unsigned int u32;
typedef __attribute__((ext_vector_type(8))) short    short8;  // bf16x8 frag
typedef __attribute__((ext_vector_type(8))) _Float16 half8;   // f16x8 frag
typedef __attribute__((ext_vector_type(4))) float    f32x4;

__device__ __forceinline__ u16 f2bf(float f) {
  u32 u = __float_as_uint(f);
  u32 r = u + 0x7fffu + ((u >> 16) & 1u);
  return (u16)(r >> 16);
}
__device__ __forceinline__ float bf2f(u16 h) { return __uint_as_float(((u32)h) << 16); }
__device__ __forceinline__ u16 f2h(float f) { return __half_as_ushort(__float2half(f)); }

__device__ __forceinline__ void gll16(const void* g, void* l) {
  __builtin_amdgcn_global_load_lds((const __attribute__((address_space(1))) void*)g,
                                   (__attribute__((address_space(3))) void*)l, 16, 0, 0);
}

// chunk-slot cumulative index per head: chunks of 8 KV tiles
__device__ __host__ __forceinline__ int cidx(int qb) {
  return qb < 8 ? qb : qb < 16 ? 8 + (qb - 8) * 2 : qb < 24 ? 24 + (qb - 16) * 3 : 48 + (qb - 24) * 4;
}

// ---------------- RoPE tables (double-accurate, rounded to fp32) ----------------
__global__ __launch_bounds__(256) void k_tables(float* __restrict__ cosb, float* __restrict__ sinb) {
  int idx = blockIdx.x * 256 + threadIdx.x;  // SQ*64
  int pos = idx >> 6, i = idx & 63;
  double f = 1.0 / pow(10000.0, (double)i / 64.0);
  float inv = (float)f;
  float ang = (float)pos * inv;
  cosb[idx] = (float)cos((double)ang);
  sinb[idx] = (float)sin((double)ang);
}

// ---------------- split x into bf16 hi/lo ----------------
__global__ __launch_bounds__(256) void k_split_x(const float* __restrict__ x,
                                                 u16* __restrict__ xh, u16* __restrict__ xl) {
  size_t base = ((size_t)blockIdx.x * 256 + threadIdx.x) * 4;
  float4 v = *(const float4*)(x + base);
  float vv[4] = {v.x, v.y, v.z, v.w};
  u16 hh[4], ll[4];
#pragma unroll
  for (int j = 0; j < 4; j++) {
    hh[j] = f2bf(vv[j]);
    ll[j] = f2bf(vv[j] - bf2f(hh[j]));
  }
  *(uint2*)(xh + base) = make_uint2((u32)hh[0] | ((u32)hh[1] << 16), (u32)hh[2] | ((u32)hh[3] << 16));
  *(uint2*)(xl + base) = make_uint2((u32)ll[0] | ((u32)ll[1] << 16), (u32)ll[2] | ((u32)ll[3] << 16));
}

// ---------------- transpose W (KxN) -> WT (NxK) with bf16 hi/lo split ----------------
__global__ __launch_bounds__(256) void k_trans_split(const float* __restrict__ src, int N,
                                                     u16* __restrict__ dh, u16* __restrict__ dl,
                                                     int rowOff) {
  __shared__ float t[64][65];
  int n0 = blockIdx.x * 64, k0 = blockIdx.y * 64;
  int tid = threadIdx.x;
  int c = tid & 63, r4 = tid >> 6;
#pragma unroll
  for (int it = 0; it < 16; it++) {
    int kk = it * 4 + r4;
    t[kk][c] = src[(size_t)(k0 + kk) * N + n0 + c];
  }
  __syncthreads();
#pragma unroll
  for (int it = 0; it < 16; it++) {
    int nn = it * 4 + r4;
    float v = t[c][nn];
    u16 hh = f2bf(v);
    size_t o = (size_t)(rowOff + n0 + nn) * 2048 + k0 + c;
    dh[o] = hh;
    dl[o] = f2bf(v - bf2f(hh));
  }
}

// ---------------- transpose wo (KxN fp32) -> woT (NxK f16) ----------------
__global__ __launch_bounds__(256) void k_trans_f16(const float* __restrict__ src, int N,
                                                   u16* __restrict__ dst) {
  __shared__ float t[64][65];
  int n0 = blockIdx.x * 64, k0 = blockIdx.y * 64;
  int tid = threadIdx.x;
  int c = tid & 63, r4 = tid >> 6;
#pragma unroll
  for (int it = 0; it < 16; it++) {
    int kk = it * 4 + r4;
    t[kk][c] = src[(size_t)(k0 + kk) * N + n0 + c];
  }
  __syncthreads();
#pragma unroll
  for (int it = 0; it < 16; it++) {
    int nn = it * 4 + r4;
    dst[(size_t)(n0 + nn) * 2048 + k0 + c] = f2h(t[c][nn]);
  }
}

// ---------------- QKV projection: bf16x3 split GEMM, 128x128 tile, BK=64 ----------------
__global__ __launch_bounds__(256) void k_gemm_qkv(
    const u16* __restrict__ xh, const u16* __restrict__ xl,
    const u16* __restrict__ wth, const u16* __restrict__ wtl,
    float* __restrict__ qkv) {
  __shared__ u16 lds[4 * 128 * 64];  // Ah | Al | Bh | Bl, 64KB
  const int tid = threadIdx.x;
  const int lane = tid & 63, wid = tid >> 6;
  const int rg = lane >> 4, c16 = lane & 15;
  const int m0 = blockIdx.y * 128, n0 = blockIdx.x * 128;
  const int wm = wid >> 1, wn = wid & 1;
  const u16* gsrc = (wid == 0) ? xh + (size_t)m0 * 2048
                  : (wid == 1) ? xl + (size_t)m0 * 2048
                  : (wid == 2) ? wth + (size_t)n0 * 2048
                               : wtl + (size_t)n0 * 2048;
  u16* ldsm = lds + wid * 8192;
  const int sr = lane >> 3, scn = lane & 7;

  f32x4 acc[4][4];
#pragma unroll
  for (int a = 0; a < 4; a++)
#pragma unroll
    for (int b = 0; b < 4; b++) acc[a][b] = (f32x4){0.f, 0.f, 0.f, 0.f};

  for (int k0 = 0; k0 < 2048; k0 += 64) {
#pragma unroll
    for (int i = 0; i < 16; i++) {
      int r = i * 8 + sr;
      int cs = (scn ^ (r & 7)) * 8;
      gll16(gsrc + (size_t)r * 2048 + k0 + cs, ldsm + i * 512);
    }
    __syncthreads();
#pragma unroll
    for (int kk = 0; kk < 2; kk++) {
      short8 ah[4], al[4], bh[4], bl[4];
      int ch = kk * 4 + rg;
#pragma unroll
      for (int mf = 0; mf < 4; mf++) {
        int m = wm * 64 + mf * 16 + c16;
        int off = m * 64 + ((ch ^ (m & 7)) * 8);
        ah[mf] = *(const short8*)(lds + off);
        al[mf] = *(const short8*)(lds + 8192 + off);
      }
#pragma unroll
      for (int nf = 0; nf < 4; nf++) {
        int n = wn * 64 + nf * 16 + c16;
        int off = n * 64 + ((ch ^ (n & 7)) * 8);
        bh[nf] = *(const short8*)(lds + 16384 + off);
        bl[nf] = *(const short8*)(lds + 24576 + off);
      }
#pragma unroll
      for (int mf = 0; mf < 4; mf++)
#pragma unroll
        for (int nf = 0; nf < 4; nf++) {
          acc[mf][nf] = __builtin_amdgcn_mfma_f32_16x16x32_bf16(ah[mf], bh[nf], acc[mf][nf], 0, 0, 0);
          acc[mf][nf] = __builtin_amdgcn_mfma_f32_16x16x32_bf16(ah[mf], bl[nf], acc[mf][nf], 0, 0, 0);
          acc[mf][nf] = __builtin_amdgcn_mfma_f32_16x16x32_bf16(al[mf], bh[nf], acc[mf][nf], 0, 0, 0);
        }
    }
    __syncthreads();
  }
#pragma unroll
  for (int mf = 0; mf < 4; mf++)
#pragma unroll
    for (int nf = 0; nf < 4; nf++)
#pragma unroll
      for (int j = 0; j < 4; j++) {
        int m = m0 + wm * 64 + mf * 16 + rg * 4 + j;
        int n = n0 + wn * 64 + nf * 16 + c16;
        qkv[(size_t)m * QKVN + n] = acc[mf][nf][j];
      }
}

// ---------------- RoPE q,k -> f16 (q pre-scaled by inv_sqrt_d*log2e) ----------------
__global__ __launch_bounds__(256) void k_rope_qk(const float* __restrict__ qkv,
                                                 const float* __restrict__ cosb,
                                                 const float* __restrict__ sinb,
                                                 u16* __restrict__ qf, u16* __restrict__ kf) {
  int idx = blockIdx.x * 256 + threadIdx.x;  // SQ*24*64
  int i = idx & 63;
  int th = idx >> 6;
  int h = th % 24, t = th / 24;
  int c0 = (h < 16) ? h * 128 + 2 * i : 2048 + (h - 16) * 128 + 2 * i;
  float2 eo = *(const float2*)(qkv + (size_t)t * QKVN + c0);
  float c = cosb[t * 64 + i], s = sinb[t * 64 + i];
  float re = eo.x * c - eo.y * s;
  float ro = eo.x * s + eo.y * c;
  if (h < 16) {
    const float QSC = (float)(1.4426950408889634 * 0.08838834764831843);  // log2e/sqrt(128)
    u32 pk = (u32)f2h(re * QSC) | ((u32)f2h(ro * QSC) << 16);
    *(u32*)(qf + ((size_t)h * SQ + t) * 128 + 2 * i) = pk;
  } else {
    u32 pk = (u32)f2h(re) | ((u32)f2h(ro) << 16);
    *(u32*)(kf + ((size_t)(h - 16) * SQ + t) * 128 + 2 * i) = pk;
  }
}

// ---------------- block means of roped k (double accumulation) ----------------
__global__ __launch_bounds__(64) void k_bm(const float* __restrict__ qkv,
                                           const float* __restrict__ cosb,
                                           const float* __restrict__ sinb,
                                           float* __restrict__ bm) {
  int hk = blockIdx.x >> 5, n = blockIdx.x & 31;
  int i = threadIdx.x;  // 64 pairs
  double se = 0.0, so = 0.0;
  for (int t = 0; t < 128; t++) {
    int tt = n * 128 + t;
    float2 eo = *(const float2*)(qkv + (size_t)tt * QKVN + 2048 + hk * 128 + 2 * i);
    float c = cosb[tt * 64 + i], s = sinb[tt * 64 + i];
    se += (double)(eo.x * c - eo.y * s);
    so += (double)(eo.x * s + eo.y * c);
  }
  float* o = bm + ((size_t)(hk * 32 + n)) * 128 + 2 * i;
  o[0] = (float)(se * (1.0 / 128.0));
  o[1] = (float)(so * (1.0 / 128.0));
}

// ---------------- gating: own-block in top-8? (only matters for b>=8) ----------------
__global__ __launch_bounds__(64) void k_gate(const float* __restrict__ qkv,
                                             const float* __restrict__ cosb,
                                             const float* __restrict__ sinb,
                                             const float* __restrict__ bm,
                                             unsigned char* __restrict__ sel) {
  __shared__ float q[64][129];
  __shared__ float bml[32 * 128];
  int bz = blockIdx.x;  // h*48 + (b-8)*2 + half
  int h = bz / 48;
  int rem = bz % 48;
  int b = 8 + (rem >> 1);
  int half = rem & 1;
  int tid = threadIdx.x;
  int hk = h >> 1;
  for (int rr = 0; rr < 64; rr++) {
    int ss = b * 128 + half * 64 + rr;
    float2 eo = *(const float2*)(qkv + (size_t)ss * QKVN + h * 128 + 2 * tid);
    float c = cosb[ss * 64 + tid], sn = sinb[ss * 64 + tid];
    q[rr][2 * tid]     = eo.x * c - eo.y * sn;
    q[rr][2 * tid + 1] = eo.x * sn + eo.y * c;
  }
  for (int o = tid; o < (b + 1) * 128; o += 64) bml[o] = bm[(size_t)hk * 32 * 128 + o];
  __syncthreads();
  int s = b * 128 + half * 64 + tid;
  double gb = 0.0;
  for (int d = 0; d < 128; d++) gb += (double)q[tid][d] * (double)bml[b * 128 + d];
  int cnt = 0;
  for (int n = 0; n < b; n++) {
    double g = 0.0;
    for (int d = 0; d < 128; d++) g += (double)q[tid][d] * (double)bml[n * 128 + d];
    cnt += (g >= gb) ? 1 : 0;
  }
  sel[h * SQ + s] = (cnt <= 7) ? 1 : 0;
}

// ---------------- transpose v -> vt[hk][d][t] f16 ----------------
__global__ __launch_bounds__(256) void k_vt(const float* __restrict__ qkv, u16* __restrict__ vt) {
  __shared__ float t[64][65];
  int hk = blockIdx.z, d0 = blockIdx.y * 64, t0 = blockIdx.x * 64;
  int tid = threadIdx.x;
  int c = tid & 63, r4 = tid >> 6;
#pragma unroll
  for (int it = 0; it < 16; it++) {
    int trow = it * 4 + r4;
    t[trow][c] = qkv[(size_t)(t0 + trow) * QKVN + 3072 + hk * 128 + d0 + c];
  }
  __syncthreads();
#pragma unroll
  for (int it = 0; it < 16; it++) {
    int dd = it * 4 + r4;
    vt[((size_t)hk * 128 + d0 + dd) * SQ + t0 + c] = f2h(t[c][dd]);
  }
}

// ---------------- split-KV flash attention chunk: no barriers, direct K/V loads ----------------
__global__ __launch_bounds__(256) void k_attn_chunk(
    const u16* __restrict__ qf, const u16* __restrict__ kf, const u16* __restrict__ vt,
    const unsigned char* __restrict__ sel, float* __restrict__ po, float* __restrict__ ml) {
  __shared__ u16 pl[4][32 * 128];  // per-wave P transpose buffer (no cross-wave sharing)
  const int L = blockIdx.x;        // [0,1280): lane-swizzled so XCD == hk
  const int hk = L & 7;
  const int c = L >> 3;            // [0,160)
  const int h = hk * 2 + (c & 1);
  const int cc = c >> 1;           // [0,80)
  int qb, chunk;
  if (cc < 8)       { qb = cc;                   chunk = 0; }
  else if (cc < 24) { qb = 8 + ((cc - 8) >> 1);  chunk = (cc - 8) & 1; }
  else if (cc < 48) { qb = 16 + (cc - 24) / 3;   chunk = (cc - 24) % 3; }
  else              { qb = 24 + ((cc - 48) >> 2); chunk = (cc - 48) & 3; }
  const int nt = (qb < 8) ? 8 : (qb + 1);
  const int tn0 = chunk * 8;
  const int tn1 = (tn0 + 8 < nt) ? tn0 + 8 : nt;
  const int tid = threadIdx.x;
  const int lane = tid & 63, wid = tid >> 6;
  const int rg = lane >> 4, c16 = lane & 15;
  const bool hasMask = (qb >= 8);

  half8 aq[2][4];
#pragma unroll
  for (int mi = 0; mi < 2; mi++)
#pragma unroll
    for (int kk = 0; kk < 4; kk++) {
      int srow = qb * 128 + wid * 32 + mi * 16 + c16;
      aq[mi][kk] = *(const half8*)(qf + ((size_t)h * SQ + srow) * 128 + kk * 32 + rg * 8);
    }

  f32x4 accO[2][8];
#pragma unroll
  for (int mi = 0; mi < 2; mi++)
#pragma unroll
    for (int nf = 0; nf < 8; nf++) accO[mi][nf] = (f32x4){0.f, 0.f, 0.f, 0.f};
  float mrun[2][4], lrun[2][4];
#pragma unroll
  for (int mi = 0; mi < 2; mi++)
#pragma unroll
    for (int j = 0; j < 4; j++) { mrun[mi][j] = -1e30f; lrun[mi][j] = 0.f; }

  bool os[2][4];
#pragma unroll
  for (int mi = 0; mi < 2; mi++)
#pragma unroll
    for (int j = 0; j < 4; j++) os[mi][j] = true;
  if (hasMask) {
#pragma unroll
    for (int mi = 0; mi < 2; mi++)
#pragma unroll
      for (int j = 0; j < 4; j++)
        os[mi][j] = sel[h * SQ + qb * 128 + wid * 32 + mi * 16 + rg * 4 + j] != 0;
  }

  const u16* kb0 = kf + (size_t)hk * SQ * 128;
  const u16* vb0 = vt + (size_t)hk * 128 * SQ;

  for (int n = tn0; n < tn1; n++) {
    const u16* kb = kb0 + (size_t)n * 128 * 128;
    f32x4 accS[2][8];
#pragma unroll
    for (int mi = 0; mi < 2; mi++)
#pragma unroll
      for (int nf = 0; nf < 8; nf++) accS[mi][nf] = (f32x4){0.f, 0.f, 0.f, 0.f};

#pragma unroll
    for (int kk = 0; kk < 4; kk++) {
      half8 bk[8];
#pragma unroll
      for (int nf = 0; nf < 8; nf++)
        bk[nf] = *(const half8*)(kb + (nf * 16 + c16) * 128 + kk * 32 + rg * 8);
#pragma unroll
      for (int nf = 0; nf < 8; nf++) {
        accS[0][nf] = __builtin_amdgcn_mfma_f32_16x16x32_f16(aq[0][kk], bk[nf], accS[0][nf], 0, 0, 0);
        accS[1][nf] = __builtin_amdgcn_mfma_f32_16x16x32_f16(aq[1][kk], bk[nf], accS[1][nf], 0, 0, 0);
      }
    }

    if (hasMask && (n == nt - 1)) {
#pragma unroll
      for (int mi = 0; mi < 2; mi++)
#pragma unroll
        for (int j = 0; j < 4; j++) {
          if (!os[mi][j]) {
            int rl = wid * 32 + mi * 16 + rg * 4 + j;
#pragma unroll
            for (int nf = 0; nf < 8; nf++) {
              int tl = nf * 16 + c16;
              if (tl > rl) accS[mi][nf][j] = -1e30f;
            }
          }
        }
    }

    // online softmax (log2 units)
#pragma unroll
    for (int mi = 0; mi < 2; mi++)
#pragma unroll
      for (int j = 0; j < 4; j++) {
        float mt = accS[mi][0][j];
#pragma unroll
        for (int nf = 1; nf < 8; nf++) mt = fmaxf(mt, accS[mi][nf][j]);
        mt = fmaxf(mt, __shfl_xor(mt, 1, 64));
        mt = fmaxf(mt, __shfl_xor(mt, 2, 64));
        mt = fmaxf(mt, __shfl_xor(mt, 4, 64));
        mt = fmaxf(mt, __shfl_xor(mt, 8, 64));
        float mnew = fmaxf(mrun[mi][j], mt);
        float sc = exp2f(mrun[mi][j] - mnew);
        mrun[mi][j] = mnew;
        float ps = 0.f;
        int rl = mi * 16 + rg * 4 + j;
#pragma unroll
        for (int nf = 0; nf < 8; nf++) {
          float p = exp2f(accS[mi][nf][j] - mnew);
          ps += p;
          int tl = nf * 16 + c16;
          pl[wid][rl * 128 + (((tl >> 3) ^ (rl & 7)) << 3) + (tl & 7)] = f2h(p);
          accO[mi][nf][j] *= sc;
        }
        ps += __shfl_xor(ps, 1, 64);
        ps += __shfl_xor(ps, 2, 64);
        ps += __shfl_xor(ps, 4, 64);
        ps += __shfl_xor(ps, 8, 64);
        lrun[mi][j] = lrun[mi][j] * sc + ps;
      }

    // PV: V fragments straight from global (vt is d-major, token-contiguous)
    const u16* vb = vb0 + n * 128;
#pragma unroll
    for (int kk = 0; kk < 4; kk++) {
      half8 pa[2];
#pragma unroll
      for (int mi = 0; mi < 2; mi++) {
        int rl = mi * 16 + c16;
        int ch = kk * 4 + rg;
        pa[mi] = *(const half8*)(&pl[wid][rl * 128 + ((ch ^ (rl & 7)) * 8)]);
      }
#pragma unroll
      for (int nf = 0; nf < 8; nf++) {
        half8 vbv = *(const half8*)(vb + (size_t)(nf * 16 + c16) * SQ + kk * 32 + rg * 8);
        accO[0][nf] = __builtin_amdgcn_mfma_f32_16x16x32_f16(pa[0], vbv, accO[0][nf], 0, 0, 0);
        accO[1][nf] = __builtin_amdgcn_mfma_f32_16x16x32_f16(pa[1], vbv, accO[1][nf], 0, 0, 0);
      }
    }
  }

  // write partials (unnormalized O + per-row m,l)
  const int pidx = h * 80 + cidx(qb) + chunk;
  float* pob = po + (size_t)pidx * 16384;
#pragma unroll
  for (int mi = 0; mi < 2; mi++)
#pragma unroll
    for (int nf = 0; nf < 8; nf++)
#pragma unroll
      for (int j = 0; j < 4; j++)
        pob[(wid * 32 + mi * 16 + rg * 4 + j) * 128 + nf * 16 + c16] = accO[mi][nf][j];
  if (c16 == 0) {
#pragma unroll
    for (int mi = 0; mi < 2; mi++)
#pragma unroll
      for (int j = 0; j < 4; j++) {
        int rl = wid * 32 + mi * 16 + rg * 4 + j;
        ml[(size_t)pidx * 256 + rl * 2]     = mrun[mi][j];
        ml[(size_t)pidx * 256 + rl * 2 + 1] = lrun[mi][j];
      }
  }
}

// ---------------- combine split-KV partials -> attn (f16) ----------------
__global__ __launch_bounds__(256) void k_attn_combine(
    const float* __restrict__ po, const float* __restrict__ ml, u16* __restrict__ attn) {
  const int qb = blockIdx.x, h = blockIdx.y;
  const int nc = (qb < 8) ? 1 : (qb < 16) ? 2 : (qb < 24) ? 3 : 4;
  const int base = h * 80 + cidx(qb);
  const int tid = threadIdx.x;
  const int r = tid >> 1, h64 = (tid & 1) * 64;
  float m[4], l[4], M = -1e30f;
#pragma unroll
  for (int ci = 0; ci < 4; ci++) {
    if (ci < nc) {
      m[ci] = ml[(size_t)(base + ci) * 256 + r * 2];
      l[ci] = ml[(size_t)(base + ci) * 256 + r * 2 + 1];
    } else { m[ci] = -1e30f; l[ci] = 0.f; }
    M = fmaxf(M, m[ci]);
  }
  float w[4], Ls = 0.f;
#pragma unroll
  for (int ci = 0; ci < 4; ci++) { w[ci] = exp2f(m[ci] - M); Ls += w[ci] * l[ci]; }
  float inv = 1.0f / Ls;
  for (int d = 0; d < 64; d += 4) {
    float4 a = make_float4(0.f, 0.f, 0.f, 0.f);
#pragma unroll
    for (int ci = 0; ci < 4; ci++) {
      if (ci < nc) {
        const float4 v = *(const float4*)&po[(size_t)(base + ci) * 16384 + r * 128 + h64 + d];
        a.x += w[ci] * v.x; a.y += w[ci] * v.y; a.z += w[ci] * v.z; a.w += w[ci] * v.w;
      }
    }
    u32 p0 = (u32)f2h(a.x * inv) | ((u32)f2h(a.y * inv) << 16);
    u32 p1 = (u32)f2h(a.z * inv) | ((u32)f2h(a.w * inv) << 16);
    *(uint2*)&attn[(size_t)(qb * 128 + r) * DIMM + h * 128 + h64 + d] = make_uint2(p0, p1);
  }
}

// ---------------- out = attn @ wo (f16 GEMM, fp32 out) ----------------
__global__ __launch_bounds__(256) void k_gemm_out(
    const u16* __restrict__ attn, const u16* __restrict__ wot, float* __restrict__ out) {
  __shared__ u16 lds[2 * 128 * 64];  // A | B, 32KB
  const int tid = threadIdx.x;
  const int lane = tid & 63, wid = tid >> 6;
  const int rg = lane >> 4, c16 = lane & 15;
  const int m0 = blockIdx.y * 128, n0 = blockIdx.x * 128;
  const int wm = wid >> 1, wn = wid & 1;
  const u16* gsrc = (wid < 2) ? attn + (size_t)m0 * 2048 : wot + (size_t)n0 * 2048;
  const int sr = lane >> 3, scn = lane & 7;

  f32x4 acc[4][4];
#pragma unroll
  for (int a = 0; a < 4; a++)
#pragma unroll
    for (int b = 0; b < 4; b++) acc[a][b] = (f32x4){0.f, 0.f, 0.f, 0.f};

  for (int k0 = 0; k0 < 2048; k0 += 64) {
#pragma unroll
    for (int i = 0; i < 8; i++) {
      int slot = wid * 8 + i;
      int s2 = slot & 15;
      int r = s2 * 8 + sr;
      int cs = (scn ^ (r & 7)) * 8;
      gll16(gsrc + (size_t)r * 2048 + k0 + cs, lds + slot * 512);
    }
    __syncthreads();
#pragma unroll
    for (int kk = 0; kk < 2; kk++) {
      half8 a[4], b[4];
      int ch = kk * 4 + rg;
#pragma unroll
      for (int mf = 0; mf < 4; mf++) {
        int m = wm * 64 + mf * 16 + c16;
        a[mf] = *(const half8*)(lds + m * 64 + ((ch ^ (m & 7)) * 8));
      }
#pragma unroll
      for (int nf = 0; nf < 4; nf++) {
        int n = wn * 64 + nf * 16 + c16;
        b[nf] = *(const half8*)(lds + 8192 + n * 64 + ((ch ^ (n & 7)) * 8));
      }
#pragma unroll
      for (int mf = 0; mf < 4; mf++)
#pragma unroll
        for (int nf = 0; nf < 4; nf++)
          acc[mf][nf] = __builtin_amdgcn_mfma_f32_16x16x32_f16(a[mf], b[nf], acc[mf][nf], 0, 0, 0);
    }
    __syncthreads();
  }
#pragma unroll
  for (int mf = 0; mf < 4; mf++)
#pragma unroll
    for (int nf = 0; nf < 4; nf++)
#pragma unroll
      for (int j = 0; j < 4; j++) {
        int m = m0 + wm * 64 + mf * 16 + rg * 4 + j;
        int n = n0 + wn * 64 + nf * 16 + c16;
        out[(size_t)m * DIMM + n] = acc[mf][nf][j];
      }
}

extern "C" void kernel_launch(void* const* d_in, const int* in_sizes, int n_in,
                              void* d_out, int out_size, void* d_ws, size_t ws_size,
                              hipStream_t stream) {
  (void)in_sizes; (void)n_in; (void)out_size; (void)ws_size;
  const float* x  = (const float*)d_in[0];
  const float* wq = (const float*)d_in[1];
  const float* wk = (const float*)d_in[2];
  const float* wv = (const float*)d_in[3];
  const float* wo = (const float*)d_in[4];
  float* out = (float*)d_out;

  char* ws = (char*)d_ws;
  const size_t MB = 1024 * 1024;
  // Region A (128MB): xh|xl|wth|wtl|qkv during projection; aliased by po|ml for split-KV
  char* A = ws;
  u16*   xh  = (u16*)(A);
  u16*   xl  = (u16*)(A + 16 * MB);
  u16*   wth = (u16*)(A + 32 * MB);
  u16*   wtl = (u16*)(A + 48 * MB);
  float* qkv = (float*)(A + 64 * MB);
  float* po  = (float*)(A);            // 80MB (1280 x 128 x 128 f32), overlays dead buffers
  float* ml  = (float*)(A + 88 * MB);  // 1.25MB, inside dead qkv region
  // Region B (persistent)
  char* B = ws + 128 * MB;
  size_t off = 0;
  auto alloc = [&](size_t b) { char* p = B + off; off += (b + 255) & ~(size_t)255; return p; };
  u16*   wot  = (u16*)alloc((size_t)DIMM * DIMM * 2);
  float* cosb = (float*)alloc((size_t)SQ * 64 * 4);
  float* sinb = (float*)alloc((size_t)SQ * 64 * 4);
  u16*   qf   = (u16*)alloc((size_t)16 * SQ * 128 * 2);
  u16*   kf   = (u16*)alloc((size_t)8 * SQ * 128 * 2);
  u16*   vt   = (u16*)alloc((size_t)8 * 128 * SQ * 2);
  float* bm   = (float*)alloc((size_t)8 * 32 * 128 * 4);
  unsigned char* sel = (unsigned char*)alloc((size_t)16 * SQ);
  u16*   attn = (u16*)alloc((size_t)SQ * DIMM * 2);

  k_tables<<<SQ * 64 / 256, 256, 0, stream>>>(cosb, sinb);
  k_split_x<<<(SQ * DIMM) / (256 * 4), 256, 0, stream>>>(x, xh, xl);
  k_trans_split<<<dim3(32, 32), 256, 0, stream>>>(wq, 2048, wth, wtl, 0);
  k_trans_split<<<dim3(16, 32), 256, 0, stream>>>(wk, 1024, wth, wtl, 2048);
  k_trans_split<<<dim3(16, 32), 256, 0, stream>>>(wv, 1024, wth, wtl, 3072);
  k_trans_f16<<<dim3(32, 32), 256, 0, stream>>>(wo, 2048, wot);
  k_gemm_qkv<<<dim3(32, 32), 256, 0, stream>>>(xh, xl, wth, wtl, qkv);
  k_rope_qk<<<(SQ * 24 * 64) / 256, 256, 0, stream>>>(qkv, cosb, sinb, qf, kf);
  k_vt<<<dim3(64, 2, 8), 256, 0, stream>>>(qkv, vt);
  k_bm<<<256, 64, 0, stream>>>(qkv, cosb, sinb, bm);
  k_gate<<<16 * 48, 64, 0, stream>>>(qkv, cosb, sinb, bm, sel);
  // qkv (and xh/xl/wth/wtl) are dead past this point -> po/ml alias them
  k_attn_chunk<<<1280, 256, 0, stream>>>(qf, kf, vt, sel, po, ml);
  k_attn_combine<<<dim3(32, 16), 256, 0, stream>>>(po, ml, attn);
  k_gemm_out<<<dim3(16, 32), 256, 0, stream>>>(attn, wot, out);
}

// Round 3
// 772.477 us; speedup vs baseline: 1.1208x; 1.1208x over previous
//
#include <hip/hip_runtime.h>
#include <hip/hip_fp16.h>

#define SQ   4096
#define DIMM 2048
#define QKVN 4096   // 2048 q | 1024 k | 1024 v

typedef unsigned short u16;
typedef unsigned int u32;
typedef __attribute__((ext_vector_type(8))) short    short8;  // bf16x8 frag
typedef __attribute__((ext_vector_type(8))) _Float16 half8;   // f16x8 frag
typedef __attribute__((ext_vector_type(4))) float    f32x4;

__device__ __forceinline__ u16 f2bf(float f) {
  u32 u = __float_as_uint(f);
  u32 r = u + 0x7fffu + ((u >> 16) & 1u);
  return (u16)(r >> 16);
}
__device__ __forceinline__ float bf2f(u16 h) { return __uint_as_float(((u32)h) << 16); }
__device__ __forceinline__ u16 f2h(float f) { return __half_as_ushort(__float2half(f)); }

__device__ __forceinline__ void gll16(const void* g, void* l) {
  __builtin_amdgcn_global_load_lds((const __attribute__((address_space(1))) void*)g,
                                   (__attribute__((address_space(3))) void*)l, 16, 0, 0);
}

// chunk-slot cumulative index per head: chunks of 8 KV tiles
__device__ __host__ __forceinline__ int cidx(int qb) {
  return qb < 8 ? qb : qb < 16 ? 8 + (qb - 8) * 2 : qb < 24 ? 24 + (qb - 16) * 3 : 48 + (qb - 24) * 4;
}

// ---------------- RoPE tables (double-accurate, rounded to fp32) ----------------
__global__ __launch_bounds__(256) void k_tables(float* __restrict__ cosb, float* __restrict__ sinb) {
  int idx = blockIdx.x * 256 + threadIdx.x;  // SQ*64
  int pos = idx >> 6, i = idx & 63;
  double f = 1.0 / pow(10000.0, (double)i / 64.0);
  float inv = (float)f;
  float ang = (float)pos * inv;
  cosb[idx] = (float)cos((double)ang);
  sinb[idx] = (float)sin((double)ang);
}

// ---------------- split x into bf16 hi/lo ----------------
__global__ __launch_bounds__(256) void k_split_x(const float* __restrict__ x,
                                                 u16* __restrict__ xh, u16* __restrict__ xl) {
  size_t base = ((size_t)blockIdx.x * 256 + threadIdx.x) * 4;
  float4 v = *(const float4*)(x + base);
  float vv[4] = {v.x, v.y, v.z, v.w};
  u16 hh[4], ll[4];
#pragma unroll
  for (int j = 0; j < 4; j++) {
    hh[j] = f2bf(vv[j]);
    ll[j] = f2bf(vv[j] - bf2f(hh[j]));
  }
  *(uint2*)(xh + base) = make_uint2((u32)hh[0] | ((u32)hh[1] << 16), (u32)hh[2] | ((u32)hh[3] << 16));
  *(uint2*)(xl + base) = make_uint2((u32)ll[0] | ((u32)ll[1] << 16), (u32)ll[2] | ((u32)ll[3] << 16));
}

// ---------------- transpose W (KxN) -> WT (NxK) with bf16 hi/lo split ----------------
__global__ __launch_bounds__(256) void k_trans_split(const float* __restrict__ src, int N,
                                                     u16* __restrict__ dh, u16* __restrict__ dl,
                                                     int rowOff) {
  __shared__ float t[64][65];
  int n0 = blockIdx.x * 64, k0 = blockIdx.y * 64;
  int tid = threadIdx.x;
  int c = tid & 63, r4 = tid >> 6;
#pragma unroll
  for (int it = 0; it < 16; it++) {
    int kk = it * 4 + r4;
    t[kk][c] = src[(size_t)(k0 + kk) * N + n0 + c];
  }
  __syncthreads();
#pragma unroll
  for (int it = 0; it < 16; it++) {
    int nn = it * 4 + r4;
    float v = t[c][nn];
    u16 hh = f2bf(v);
    size_t o = (size_t)(rowOff + n0 + nn) * 2048 + k0 + c;
    dh[o] = hh;
    dl[o] = f2bf(v - bf2f(hh));
  }
}

// ---------------- transpose wo (KxN fp32) -> woT (NxK f16) ----------------
__global__ __launch_bounds__(256) void k_trans_f16(const float* __restrict__ src, int N,
                                                   u16* __restrict__ dst) {
  __shared__ float t[64][65];
  int n0 = blockIdx.x * 64, k0 = blockIdx.y * 64;
  int tid = threadIdx.x;
  int c = tid & 63, r4 = tid >> 6;
#pragma unroll
  for (int it = 0; it < 16; it++) {
    int kk = it * 4 + r4;
    t[kk][c] = src[(size_t)(k0 + kk) * N + n0 + c];
  }
  __syncthreads();
#pragma unroll
  for (int it = 0; it < 16; it++) {
    int nn = it * 4 + r4;
    dst[(size_t)(n0 + nn) * 2048 + k0 + c] = f2h(t[c][nn]);
  }
}

// ---------------- QKV projection: bf16x3 split GEMM, 128x128 tile, BK=64 ----------------
__global__ __launch_bounds__(256) void k_gemm_qkv(
    const u16* __restrict__ xh, const u16* __restrict__ xl,
    const u16* __restrict__ wth, const u16* __restrict__ wtl,
    float* __restrict__ qkv) {
  __shared__ u16 lds[4 * 128 * 64];  // Ah | Al | Bh | Bl, 64KB
  const int tid = threadIdx.x;
  const int lane = tid & 63, wid = tid >> 6;
  const int rg = lane >> 4, c16 = lane & 15;
  const int m0 = blockIdx.y * 128, n0 = blockIdx.x * 128;
  const int wm = wid >> 1, wn = wid & 1;
  const u16* gsrc = (wid == 0) ? xh + (size_t)m0 * 2048
                  : (wid == 1) ? xl + (size_t)m0 * 2048
                  : (wid == 2) ? wth + (size_t)n0 * 2048
                               : wtl + (size_t)n0 * 2048;
  u16* ldsm = lds + wid * 8192;
  const int sr = lane >> 3, scn = lane & 7;

  f32x4 acc[4][4];
#pragma unroll
  for (int a = 0; a < 4; a++)
#pragma unroll
    for (int b = 0; b < 4; b++) acc[a][b] = (f32x4){0.f, 0.f, 0.f, 0.f};

  for (int k0 = 0; k0 < 2048; k0 += 64) {
#pragma unroll
    for (int i = 0; i < 16; i++) {
      int r = i * 8 + sr;
      int cs = (scn ^ (r & 7)) * 8;
      gll16(gsrc + (size_t)r * 2048 + k0 + cs, ldsm + i * 512);
    }
    __syncthreads();
#pragma unroll
    for (int kk = 0; kk < 2; kk++) {
      short8 ah[4], al[4], bh[4], bl[4];
      int ch = kk * 4 + rg;
#pragma unroll
      for (int mf = 0; mf < 4; mf++) {
        int m = wm * 64 + mf * 16 + c16;
        int off = m * 64 + ((ch ^ (m & 7)) * 8);
        ah[mf] = *(const short8*)(lds + off);
        al[mf] = *(const short8*)(lds + 8192 + off);
      }
#pragma unroll
      for (int nf = 0; nf < 4; nf++) {
        int n = wn * 64 + nf * 16 + c16;
        int off = n * 64 + ((ch ^ (n & 7)) * 8);
        bh[nf] = *(const short8*)(lds + 16384 + off);
        bl[nf] = *(const short8*)(lds + 24576 + off);
      }
#pragma unroll
      for (int mf = 0; mf < 4; mf++)
#pragma unroll
        for (int nf = 0; nf < 4; nf++) {
          acc[mf][nf] = __builtin_amdgcn_mfma_f32_16x16x32_bf16(ah[mf], bh[nf], acc[mf][nf], 0, 0, 0);
          acc[mf][nf] = __builtin_amdgcn_mfma_f32_16x16x32_bf16(ah[mf], bl[nf], acc[mf][nf], 0, 0, 0);
          acc[mf][nf] = __builtin_amdgcn_mfma_f32_16x16x32_bf16(al[mf], bh[nf], acc[mf][nf], 0, 0, 0);
        }
    }
    __syncthreads();
  }
#pragma unroll
  for (int mf = 0; mf < 4; mf++)
#pragma unroll
    for (int nf = 0; nf < 4; nf++)
#pragma unroll
      for (int j = 0; j < 4; j++) {
        int m = m0 + wm * 64 + mf * 16 + rg * 4 + j;
        int n = n0 + wn * 64 + nf * 16 + c16;
        qkv[(size_t)m * QKVN + n] = acc[mf][nf][j];
      }
}

// ---------------- RoPE q,k -> f16 (q pre-scaled by inv_sqrt_d*log2e) ----------------
__global__ __launch_bounds__(256) void k_rope_qk(const float* __restrict__ qkv,
                                                 const float* __restrict__ cosb,
                                                 const float* __restrict__ sinb,
                                                 u16* __restrict__ qf, u16* __restrict__ kf) {
  int idx = blockIdx.x * 256 + threadIdx.x;  // SQ*24*64
  int i = idx & 63;
  int th = idx >> 6;
  int h = th % 24, t = th / 24;
  int c0 = (h < 16) ? h * 128 + 2 * i : 2048 + (h - 16) * 128 + 2 * i;
  float2 eo = *(const float2*)(qkv + (size_t)t * QKVN + c0);
  float c = cosb[t * 64 + i], s = sinb[t * 64 + i];
  float re = eo.x * c - eo.y * s;
  float ro = eo.x * s + eo.y * c;
  if (h < 16) {
    const float QSC = (float)(1.4426950408889634 * 0.08838834764831843);  // log2e/sqrt(128)
    u32 pk = (u32)f2h(re * QSC) | ((u32)f2h(ro * QSC) << 16);
    *(u32*)(qf + ((size_t)h * SQ + t) * 128 + 2 * i) = pk;
  } else {
    u32 pk = (u32)f2h(re) | ((u32)f2h(ro) << 16);
    *(u32*)(kf + ((size_t)(h - 16) * SQ + t) * 128 + 2 * i) = pk;
  }
}

// ---------------- block means of roped k (double accumulation) ----------------
__global__ __launch_bounds__(64) void k_bm(const float* __restrict__ qkv,
                                           const float* __restrict__ cosb,
                                           const float* __restrict__ sinb,
                                           float* __restrict__ bm) {
  int hk = blockIdx.x >> 5, n = blockIdx.x & 31;
  int i = threadIdx.x;  // 64 pairs
  double se = 0.0, so = 0.0;
  for (int t = 0; t < 128; t++) {
    int tt = n * 128 + t;
    float2 eo = *(const float2*)(qkv + (size_t)tt * QKVN + 2048 + hk * 128 + 2 * i);
    float c = cosb[tt * 64 + i], s = sinb[tt * 64 + i];
    se += (double)(eo.x * c - eo.y * s);
    so += (double)(eo.x * s + eo.y * c);
  }
  float* o = bm + ((size_t)(hk * 32 + n)) * 128 + 2 * i;
  o[0] = (float)(se * (1.0 / 128.0));
  o[1] = (float)(so * (1.0 / 128.0));
}

// ---------------- gating: own-block in top-8? (only matters for b>=8) ----------------
__global__ __launch_bounds__(64) void k_gate(const float* __restrict__ qkv,
                                             const float* __restrict__ cosb,
                                             const float* __restrict__ sinb,
                                             const float* __restrict__ bm,
                                             unsigned char* __restrict__ sel) {
  __shared__ float q[64][129];
  __shared__ float bml[32 * 128];
  int bz = blockIdx.x;  // h*48 + (b-8)*2 + half
  int h = bz / 48;
  int rem = bz % 48;
  int b = 8 + (rem >> 1);
  int half = rem & 1;
  int tid = threadIdx.x;
  int hk = h >> 1;
  for (int rr = 0; rr < 64; rr++) {
    int ss = b * 128 + half * 64 + rr;
    float2 eo = *(const float2*)(qkv + (size_t)ss * QKVN + h * 128 + 2 * tid);
    float c = cosb[ss * 64 + tid], sn = sinb[ss * 64 + tid];
    q[rr][2 * tid]     = eo.x * c - eo.y * sn;
    q[rr][2 * tid + 1] = eo.x * sn + eo.y * c;
  }
  for (int o = tid; o < (b + 1) * 128; o += 64) bml[o] = bm[(size_t)hk * 32 * 128 + o];
  __syncthreads();
  int s = b * 128 + half * 64 + tid;
  double gb = 0.0;
  for (int d = 0; d < 128; d++) gb += (double)q[tid][d] * (double)bml[b * 128 + d];
  int cnt = 0;
  for (int n = 0; n < b; n++) {
    double g = 0.0;
    for (int d = 0; d < 128; d++) g += (double)q[tid][d] * (double)bml[n * 128 + d];
    cnt += (g >= gb) ? 1 : 0;
  }
  sel[h * SQ + s] = (cnt <= 7) ? 1 : 0;
}

// ---------------- transpose v -> vt[hk][d][t] f16 ----------------
__global__ __launch_bounds__(256) void k_vt(const float* __restrict__ qkv, u16* __restrict__ vt) {
  __shared__ float t[64][65];
  int hk = blockIdx.z, d0 = blockIdx.y * 64, t0 = blockIdx.x * 64;
  int tid = threadIdx.x;
  int c = tid & 63, r4 = tid >> 6;
#pragma unroll
  for (int it = 0; it < 16; it++) {
    int trow = it * 4 + r4;
    t[trow][c] = qkv[(size_t)(t0 + trow) * QKVN + 3072 + hk * 128 + d0 + c];
  }
  __syncthreads();
#pragma unroll
  for (int it = 0; it < 16; it++) {
    int dd = it * 4 + r4;
    vt[((size_t)hk * 128 + d0 + dd) * SQ + t0 + c] = f2h(t[c][dd]);
  }
}

// ---------------- split-KV flash attention: swapped-operand, all-register softmax ----------------
// S^T = mfma(K, Q): q-row lands on lane&15; permuted K-row assignment makes the
// S^T output registers exactly the PV B-fragment (P^T) layout -> zero cross-lane
// P movement, no P LDS. PV swapped too (O^T = mfma(V^T, P^T)) so m/l/rescale are
// pure per-lane. Row reduce = in-lane tree + shfl_xor(16) + shfl_xor(32).
__global__ __launch_bounds__(256) void k_attn_chunk(
    const u16* __restrict__ qf, const u16* __restrict__ kf, const u16* __restrict__ vt,
    const unsigned char* __restrict__ sel, float* __restrict__ po, float* __restrict__ ml) {
  const int L = blockIdx.x;        // [0,1280): laid out so XCD == hk
  const int hk = L & 7;
  const int c = L >> 3;            // [0,160)
  const int h = hk * 2 + (c & 1);
  const int cc = c >> 1;           // [0,80)
  int qb, chunk;
  if (cc < 8)       { qb = cc;                   chunk = 0; }
  else if (cc < 24) { qb = 8 + ((cc - 8) >> 1);  chunk = (cc - 8) & 1; }
  else if (cc < 48) { qb = 16 + (cc - 24) / 3;   chunk = (cc - 24) % 3; }
  else              { qb = 24 + ((cc - 48) >> 2); chunk = (cc - 48) & 3; }
  const int nt = (qb < 8) ? 8 : (qb + 1);
  const int tn0 = chunk * 8;
  const int tn1 = (tn0 + 8 < nt) ? tn0 + 8 : nt;
  const int tid = threadIdx.x;
  const int lane = tid & 63, wid = tid >> 6;
  const int rg = lane >> 4, c16 = lane & 15;
  const bool hasMask = (qb >= 8);

  // Q fragments (B-operand of S^T): B[k=d][col=q] -> same layout as A-frag load
  half8 aq[2][4];
#pragma unroll
  for (int mi = 0; mi < 2; mi++)
#pragma unroll
    for (int dk = 0; dk < 4; dk++) {
      int srow = qb * 128 + wid * 32 + mi * 16 + c16;
      aq[mi][dk] = *(const half8*)(qf + ((size_t)h * SQ + srow) * 128 + dk * 32 + rg * 8);
    }

  f32x4 accO[2][8];  // O^T: col=lane&15=q(frag mi), row=rg*4+j = d within nf window
#pragma unroll
  for (int mi = 0; mi < 2; mi++)
#pragma unroll
    for (int nf = 0; nf < 8; nf++) accO[mi][nf] = (f32x4){0.f, 0.f, 0.f, 0.f};
  float mrun[2] = {-1e30f, -1e30f}, lrun[2] = {0.f, 0.f};

  bool os2[2] = {true, true};
  if (hasMask) {
#pragma unroll
    for (int mi = 0; mi < 2; mi++)
      os2[mi] = sel[h * SQ + qb * 128 + wid * 32 + mi * 16 + c16] != 0;
  }

  const u16* kb0 = kf + (size_t)hk * SQ * 128;
  const u16* vb0 = vt + (size_t)hk * 128 * SQ;
  // permuted K-row token for this lane (relative to kk*32): (c16>>2)*8 + half*4 + (c16&3)
  const int tokp = ((c16 >> 2) << 3) + (c16 & 3);

  for (int n = tn0; n < tn1; n++) {
    const u16* kb = kb0 + (size_t)n * 128 * 128;
    const u16* vb = vb0 + n * 128;

    f32x4 st[4][2][2];  // [kk][half][mi]
#pragma unroll
    for (int kk = 0; kk < 4; kk++)
#pragma unroll
      for (int hf = 0; hf < 2; hf++)
#pragma unroll
        for (int mi = 0; mi < 2; mi++) st[kk][hf][mi] = (f32x4){0.f, 0.f, 0.f, 0.f};

    // QK^T (swapped): A = permuted K rows, B = Q
#pragma unroll
    for (int kk = 0; kk < 4; kk++)
#pragma unroll
      for (int hf = 0; hf < 2; hf++) {
        const u16* kr = kb + (kk * 32 + tokp + hf * 4) * 128 + rg * 8;
#pragma unroll
        for (int dk = 0; dk < 4; dk++) {
          half8 ka = *(const half8*)(kr + dk * 32);
          st[kk][hf][0] = __builtin_amdgcn_mfma_f32_16x16x32_f16(ka, aq[0][dk], st[kk][hf][0], 0, 0, 0);
          st[kk][hf][1] = __builtin_amdgcn_mfma_f32_16x16x32_f16(ka, aq[1][dk], st[kk][hf][1], 0, 0, 0);
        }
      }

    // prefetch V for kk=0 (hides L2 latency under softmax)
    half8 v0[8];
#pragma unroll
    for (int nf = 0; nf < 8; nf++)
      v0[nf] = *(const half8*)(vb + (size_t)(nf * 16 + c16) * SQ + rg * 8);

    if (hasMask && (n == nt - 1)) {
#pragma unroll
      for (int mi = 0; mi < 2; mi++) {
        if (!os2[mi]) {
          int row = wid * 32 + mi * 16 + c16;
#pragma unroll
          for (int kk = 0; kk < 4; kk++)
#pragma unroll
            for (int hf = 0; hf < 2; hf++)
#pragma unroll
              for (int j = 0; j < 4; j++) {
                int t = kk * 32 + rg * 8 + hf * 4 + j;
                if (t > row) st[kk][hf][mi][j] = -1e30f;
              }
        }
      }
    }

    // online softmax, fully per-lane (q-row = c16 of frag mi)
#pragma unroll
    for (int mi = 0; mi < 2; mi++) {
      float mt = -1e30f;
#pragma unroll
      for (int kk = 0; kk < 4; kk++)
#pragma unroll
        for (int hf = 0; hf < 2; hf++)
#pragma unroll
          for (int j = 0; j < 4; j++) mt = fmaxf(mt, st[kk][hf][mi][j]);
      mt = fmaxf(mt, __shfl_xor(mt, 16, 64));
      mt = fmaxf(mt, __shfl_xor(mt, 32, 64));
      float mnew = fmaxf(mrun[mi], mt);
      float sc = exp2f(mrun[mi] - mnew);
      mrun[mi] = mnew;
      float ps = 0.f;
#pragma unroll
      for (int kk = 0; kk < 4; kk++)
#pragma unroll
        for (int hf = 0; hf < 2; hf++)
#pragma unroll
          for (int j = 0; j < 4; j++) {
            float p = exp2f(st[kk][hf][mi][j] - mnew);
            st[kk][hf][mi][j] = p;
            ps += p;
          }
      ps += __shfl_xor(ps, 16, 64);
      ps += __shfl_xor(ps, 32, 64);
      lrun[mi] = lrun[mi] * sc + ps;
#pragma unroll
      for (int nf = 0; nf < 8; nf++) accO[mi][nf] *= sc;
    }

    // pack P^T fragments: e = hf*4 + j  (scalar casts; compiler packs)
    half8 pa[4][2];
#pragma unroll
    for (int kk = 0; kk < 4; kk++)
#pragma unroll
      for (int mi = 0; mi < 2; mi++) {
        union { half8 v; _Float16 e[8]; } pu;
#pragma unroll
        for (int hf = 0; hf < 2; hf++)
#pragma unroll
          for (int j = 0; j < 4; j++)
            pu.e[hf * 4 + j] = (_Float16)st[kk][hf][mi][j];
        pa[kk][mi] = pu.v;
      }

    // PV (swapped): A = V^T rows (d on lane&15), B = P^T
#pragma unroll
    for (int kk = 0; kk < 4; kk++)
#pragma unroll
      for (int nf = 0; nf < 8; nf++) {
        half8 va = (kk == 0) ? v0[nf]
                 : *(const half8*)(vb + (size_t)(nf * 16 + c16) * SQ + kk * 32 + rg * 8);
        accO[0][nf] = __builtin_amdgcn_mfma_f32_16x16x32_f16(va, pa[kk][0], accO[0][nf], 0, 0, 0);
        accO[1][nf] = __builtin_amdgcn_mfma_f32_16x16x32_f16(va, pa[kk][1], accO[1][nf], 0, 0, 0);
      }
  }

  // write partials: po row=q, col=d (accO j-elems are d-contiguous -> float4 stores)
  const int pidx = h * 80 + cidx(qb) + chunk;
  float* pob = po + (size_t)pidx * 16384;
#pragma unroll
  for (int mi = 0; mi < 2; mi++) {
    int row = wid * 32 + mi * 16 + c16;
#pragma unroll
    for (int nf = 0; nf < 8; nf++)
      *(f32x4*)&pob[row * 128 + nf * 16 + rg * 4] = accO[mi][nf];
  }
  if (rg == 0) {
#pragma unroll
    for (int mi = 0; mi < 2; mi++) {
      int row = wid * 32 + mi * 16 + c16;
      ml[(size_t)pidx * 256 + row * 2]     = mrun[mi];
      ml[(size_t)pidx * 256 + row * 2 + 1] = lrun[mi];
    }
  }
}

// ---------------- combine split-KV partials -> attn (f16) ----------------
__global__ __launch_bounds__(256) void k_attn_combine(
    const float* __restrict__ po, const float* __restrict__ ml, u16* __restrict__ attn) {
  const int qb = blockIdx.x, h = blockIdx.y;
  const int nc = (qb < 8) ? 1 : (qb < 16) ? 2 : (qb < 24) ? 3 : 4;
  const int base = h * 80 + cidx(qb);
  const int tid = threadIdx.x;
  const int r = tid >> 1, h64 = (tid & 1) * 64;
  float m[4], l[4], M = -1e30f;
#pragma unroll
  for (int ci = 0; ci < 4; ci++) {
    if (ci < nc) {
      m[ci] = ml[(size_t)(base + ci) * 256 + r * 2];
      l[ci] = ml[(size_t)(base + ci) * 256 + r * 2 + 1];
    } else { m[ci] = -1e30f; l[ci] = 0.f; }
    M = fmaxf(M, m[ci]);
  }
  float w[4], Ls = 0.f;
#pragma unroll
  for (int ci = 0; ci < 4; ci++) { w[ci] = exp2f(m[ci] - M); Ls += w[ci] * l[ci]; }
  float inv = 1.0f / Ls;
  for (int d = 0; d < 64; d += 4) {
    float4 a = make_float4(0.f, 0.f, 0.f, 0.f);
#pragma unroll
    for (int ci = 0; ci < 4; ci++) {
      if (ci < nc) {
        const float4 v = *(const float4*)&po[(size_t)(base + ci) * 16384 + r * 128 + h64 + d];
        a.x += w[ci] * v.x; a.y += w[ci] * v.y; a.z += w[ci] * v.z; a.w += w[ci] * v.w;
      }
    }
    u32 p0 = (u32)f2h(a.x * inv) | ((u32)f2h(a.y * inv) << 16);
    u32 p1 = (u32)f2h(a.z * inv) | ((u32)f2h(a.w * inv) << 16);
    *(uint2*)&attn[(size_t)(qb * 128 + r) * DIMM + h * 128 + h64 + d] = make_uint2(p0, p1);
  }
}

// ---------------- out = attn @ wo (f16 GEMM, fp32 out) ----------------
__global__ __launch_bounds__(256) void k_gemm_out(
    const u16* __restrict__ attn, const u16* __restrict__ wot, float* __restrict__ out) {
  __shared__ u16 lds[2 * 128 * 64];  // A | B, 32KB
  const int tid = threadIdx.x;
  const int lane = tid & 63, wid = tid >> 6;
  const int rg = lane >> 4, c16 = lane & 15;
  const int m0 = blockIdx.y * 128, n0 = blockIdx.x * 128;
  const int wm = wid >> 1, wn = wid & 1;
  const u16* gsrc = (wid < 2) ? attn + (size_t)m0 * 2048 : wot + (size_t)n0 * 2048;
  const int sr = lane >> 3, scn = lane & 7;

  f32x4 acc[4][4];
#pragma unroll
  for (int a = 0; a < 4; a++)
#pragma unroll
    for (int b = 0; b < 4; b++) acc[a][b] = (f32x4){0.f, 0.f, 0.f, 0.f};

  for (int k0 = 0; k0 < 2048; k0 += 64) {
#pragma unroll
    for (int i = 0; i < 8; i++) {
      int slot = wid * 8 + i;
      int s2 = slot & 15;
      int r = s2 * 8 + sr;
      int cs = (scn ^ (r & 7)) * 8;
      gll16(gsrc + (size_t)r * 2048 + k0 + cs, lds + slot * 512);
    }
    __syncthreads();
#pragma unroll
    for (int kk = 0; kk < 2; kk++) {
      half8 a[4], b[4];
      int ch = kk * 4 + rg;
#pragma unroll
      for (int mf = 0; mf < 4; mf++) {
        int m = wm * 64 + mf * 16 + c16;
        a[mf] = *(const half8*)(lds + m * 64 + ((ch ^ (m & 7)) * 8));
      }
#pragma unroll
      for (int nf = 0; nf < 4; nf++) {
        int n = wn * 64 + nf * 16 + c16;
        b[nf] = *(const half8*)(lds + 8192 + n * 64 + ((ch ^ (n & 7)) * 8));
      }
#pragma unroll
      for (int mf = 0; mf < 4; mf++)
#pragma unroll
        for (int nf = 0; nf < 4; nf++)
          acc[mf][nf] = __builtin_amdgcn_mfma_f32_16x16x32_f16(a[mf], b[nf], acc[mf][nf], 0, 0, 0);
    }
    __syncthreads();
  }
#pragma unroll
  for (int mf = 0; mf < 4; mf++)
#pragma unroll
    for (int nf = 0; nf < 4; nf++)
#pragma unroll
      for (int j = 0; j < 4; j++) {
        int m = m0 + wm * 64 + mf * 16 + rg * 4 + j;
        int n = n0 + wn * 64 + nf * 16 + c16;
        out[(size_t)m * DIMM + n] = acc[mf][nf][j];
      }
}

extern "C" void kernel_launch(void* const* d_in, const int* in_sizes, int n_in,
                              void* d_out, int out_size, void* d_ws, size_t ws_size,
                              hipStream_t stream) {
  (void)in_sizes; (void)n_in; (void)out_size; (void)ws_size;
  const float* x  = (const float*)d_in[0];
  const float* wq = (const float*)d_in[1];
  const float* wk = (const float*)d_in[2];
  const float* wv = (const float*)d_in[3];
  const float* wo = (const float*)d_in[4];
  float* out = (float*)d_out;

  char* ws = (char*)d_ws;
  const size_t MB = 1024 * 1024;
  // Region A (128MB): xh|xl|wth|wtl|qkv during projection; aliased by po|ml for split-KV
  char* A = ws;
  u16*   xh  = (u16*)(A);
  u16*   xl  = (u16*)(A + 16 * MB);
  u16*   wth = (u16*)(A + 32 * MB);
  u16*   wtl = (u16*)(A + 48 * MB);
  float* qkv = (float*)(A + 64 * MB);
  float* po  = (float*)(A);            // 80MB (1280 x 128 x 128 f32), overlays dead buffers
  float* ml  = (float*)(A + 88 * MB);  // 1.25MB, inside dead qkv region
  // Region B (persistent)
  char* B = ws + 128 * MB;
  size_t off = 0;
  auto alloc = [&](size_t b) { char* p = B + off; off += (b + 255) & ~(size_t)255; return p; };
  u16*   wot  = (u16*)alloc((size_t)DIMM * DIMM * 2);
  float* cosb = (float*)alloc((size_t)SQ * 64 * 4);
  float* sinb = (float*)alloc((size_t)SQ * 64 * 4);
  u16*   qf   = (u16*)alloc((size_t)16 * SQ * 128 * 2);
  u16*   kf   = (u16*)alloc((size_t)8 * SQ * 128 * 2);
  u16*   vt   = (u16*)alloc((size_t)8 * 128 * SQ * 2);
  float* bm   = (float*)alloc((size_t)8 * 32 * 128 * 4);
  unsigned char* sel = (unsigned char*)alloc((size_t)16 * SQ);
  u16*   attn = (u16*)alloc((size_t)SQ * DIMM * 2);

  k_tables<<<SQ * 64 / 256, 256, 0, stream>>>(cosb, sinb);
  k_split_x<<<(SQ * DIMM) / (256 * 4), 256, 0, stream>>>(x, xh, xl);
  k_trans_split<<<dim3(32, 32), 256, 0, stream>>>(wq, 2048, wth, wtl, 0);
  k_trans_split<<<dim3(16, 32), 256, 0, stream>>>(wk, 1024, wth, wtl, 2048);
  k_trans_split<<<dim3(16, 32), 256, 0, stream>>>(wv, 1024, wth, wtl, 3072);
  k_trans_f16<<<dim3(32, 32), 256, 0, stream>>>(wo, 2048, wot);
  k_gemm_qkv<<<dim3(32, 32), 256, 0, stream>>>(xh, xl, wth, wtl, qkv);
  k_rope_qk<<<(SQ * 24 * 64) / 256, 256, 0, stream>>>(qkv, cosb, sinb, qf, kf);
  k_vt<<<dim3(64, 2, 8), 256, 0, stream>>>(qkv, vt);
  k_bm<<<256, 64, 0, stream>>>(qkv, cosb, sinb, bm);
  k_gate<<<16 * 48, 64, 0, stream>>>(qkv, cosb, sinb, bm, sel);
  // qkv (and xh/xl/wth/wtl) are dead past this point -> po/ml alias them
  k_attn_chunk<<<1280, 256, 0, stream>>>(qf, kf, vt, sel, po, ml);
  k_attn_combine<<<dim3(32, 16), 256, 0, stream>>>(po, ml, attn);
  k_gemm_out<<<dim3(16, 32), 256, 0, stream>>>(attn, wot, out);
}

// Round 4
// 612.881 us; speedup vs baseline: 1.4126x; 1.2604x over previous
//
#include <hip/hip_runtime.h>
#include <hip/hip_fp16.h>

#define SQ   4096
#define DIMM 2048
#define QKVN 4096   // 2048 q | 1024 k | 1024 v

typedef unsigned short u16;
typedef unsigned int u32;
typedef __attribute__((ext_vector_type(8))) short    short8;  // bf16x8 frag
typedef __attribute__((ext_vector_type(8))) _Float16 half8;   // f16x8 frag
typedef __attribute__((ext_vector_type(4))) float    f32x4;

__device__ __forceinline__ u16 f2bf(float f) {
  u32 u = __float_as_uint(f);
  u32 r = u + 0x7fffu + ((u >> 16) & 1u);
  return (u16)(r >> 16);
}
__device__ __forceinline__ float bf2f(u16 h) { return __uint_as_float(((u32)h) << 16); }
__device__ __forceinline__ u16 f2h(float f) { return __half_as_ushort(__float2half(f)); }

__device__ __forceinline__ void gll16(const void* g, void* l) {
  __builtin_amdgcn_global_load_lds((const __attribute__((address_space(1))) void*)g,
                                   (__attribute__((address_space(3))) void*)l, 16, 0, 0);
}

// chunk-slot cumulative index per head: chunks of 8 KV blocks (128-token units)
__device__ __host__ __forceinline__ int cidx(int qb) {
  return qb < 8 ? qb : qb < 16 ? 8 + (qb - 8) * 2 : qb < 24 ? 24 + (qb - 16) * 3 : 48 + (qb - 24) * 4;
}

// ---------------- RoPE tables (double-accurate, rounded to fp32) ----------------
__global__ __launch_bounds__(256) void k_tables(float* __restrict__ cosb, float* __restrict__ sinb) {
  int idx = blockIdx.x * 256 + threadIdx.x;  // SQ*64
  int pos = idx >> 6, i = idx & 63;
  double f = 1.0 / pow(10000.0, (double)i / 64.0);
  float inv = (float)f;
  float ang = (float)pos * inv;
  cosb[idx] = (float)cos((double)ang);
  sinb[idx] = (float)sin((double)ang);
}

// ---------------- split x into bf16 hi/lo ----------------
__global__ __launch_bounds__(256) void k_split_x(const float* __restrict__ x,
                                                 u16* __restrict__ xh, u16* __restrict__ xl) {
  size_t base = ((size_t)blockIdx.x * 256 + threadIdx.x) * 4;
  float4 v = *(const float4*)(x + base);
  float vv[4] = {v.x, v.y, v.z, v.w};
  u16 hh[4], ll[4];
#pragma unroll
  for (int j = 0; j < 4; j++) {
    hh[j] = f2bf(vv[j]);
    ll[j] = f2bf(vv[j] - bf2f(hh[j]));
  }
  *(uint2*)(xh + base) = make_uint2((u32)hh[0] | ((u32)hh[1] << 16), (u32)hh[2] | ((u32)hh[3] << 16));
  *(uint2*)(xl + base) = make_uint2((u32)ll[0] | ((u32)ll[1] << 16), (u32)ll[2] | ((u32)ll[3] << 16));
}

// ---------------- transpose W (KxN) -> WT (NxK) with bf16 hi/lo split ----------------
__global__ __launch_bounds__(256) void k_trans_split(const float* __restrict__ src, int N,
                                                     u16* __restrict__ dh, u16* __restrict__ dl,
                                                     int rowOff) {
  __shared__ float t[64][65];
  int n0 = blockIdx.x * 64, k0 = blockIdx.y * 64;
  int tid = threadIdx.x;
  int c = tid & 63, r4 = tid >> 6;
#pragma unroll
  for (int it = 0; it < 16; it++) {
    int kk = it * 4 + r4;
    t[kk][c] = src[(size_t)(k0 + kk) * N + n0 + c];
  }
  __syncthreads();
#pragma unroll
  for (int it = 0; it < 16; it++) {
    int nn = it * 4 + r4;
    float v = t[c][nn];
    u16 hh = f2bf(v);
    size_t o = (size_t)(rowOff + n0 + nn) * 2048 + k0 + c;
    dh[o] = hh;
    dl[o] = f2bf(v - bf2f(hh));
  }
}

// ---------------- transpose wo (KxN fp32) -> woT (NxK f16) ----------------
__global__ __launch_bounds__(256) void k_trans_f16(const float* __restrict__ src, int N,
                                                   u16* __restrict__ dst) {
  __shared__ float t[64][65];
  int n0 = blockIdx.x * 64, k0 = blockIdx.y * 64;
  int tid = threadIdx.x;
  int c = tid & 63, r4 = tid >> 6;
#pragma unroll
  for (int it = 0; it < 16; it++) {
    int kk = it * 4 + r4;
    t[kk][c] = src[(size_t)(k0 + kk) * N + n0 + c];
  }
  __syncthreads();
#pragma unroll
  for (int it = 0; it < 16; it++) {
    int nn = it * 4 + r4;
    dst[(size_t)(n0 + nn) * 2048 + k0 + c] = f2h(t[c][nn]);
  }
}

// ---------------- QKV projection: bf16x3 split GEMM, 128x128 tile, BK=64 ----------------
__global__ __launch_bounds__(256) void k_gemm_qkv(
    const u16* __restrict__ xh, const u16* __restrict__ xl,
    const u16* __restrict__ wth, const u16* __restrict__ wtl,
    float* __restrict__ qkv) {
  __shared__ u16 lds[4 * 128 * 64];  // Ah | Al | Bh | Bl, 64KB
  const int tid = threadIdx.x;
  const int lane = tid & 63, wid = tid >> 6;
  const int rg = lane >> 4, c16 = lane & 15;
  const int m0 = blockIdx.y * 128, n0 = blockIdx.x * 128;
  const int wm = wid >> 1, wn = wid & 1;
  const u16* gsrc = (wid == 0) ? xh + (size_t)m0 * 2048
                  : (wid == 1) ? xl + (size_t)m0 * 2048
                  : (wid == 2) ? wth + (size_t)n0 * 2048
                               : wtl + (size_t)n0 * 2048;
  u16* ldsm = lds + wid * 8192;
  const int sr = lane >> 3, scn = lane & 7;

  f32x4 acc[4][4];
#pragma unroll
  for (int a = 0; a < 4; a++)
#pragma unroll
    for (int b = 0; b < 4; b++) acc[a][b] = (f32x4){0.f, 0.f, 0.f, 0.f};

  for (int k0 = 0; k0 < 2048; k0 += 64) {
#pragma unroll
    for (int i = 0; i < 16; i++) {
      int r = i * 8 + sr;
      int cs = (scn ^ (r & 7)) * 8;
      gll16(gsrc + (size_t)r * 2048 + k0 + cs, ldsm + i * 512);
    }
    __syncthreads();
#pragma unroll
    for (int kk = 0; kk < 2; kk++) {
      short8 ah[4], al[4], bh[4], bl[4];
      int ch = kk * 4 + rg;
#pragma unroll
      for (int mf = 0; mf < 4; mf++) {
        int m = wm * 64 + mf * 16 + c16;
        int off = m * 64 + ((ch ^ (m & 7)) * 8);
        ah[mf] = *(const short8*)(lds + off);
        al[mf] = *(const short8*)(lds + 8192 + off);
      }
#pragma unroll
      for (int nf = 0; nf < 4; nf++) {
        int n = wn * 64 + nf * 16 + c16;
        int off = n * 64 + ((ch ^ (n & 7)) * 8);
        bh[nf] = *(const short8*)(lds + 16384 + off);
        bl[nf] = *(const short8*)(lds + 24576 + off);
      }
#pragma unroll
      for (int mf = 0; mf < 4; mf++)
#pragma unroll
        for (int nf = 0; nf < 4; nf++) {
          acc[mf][nf] = __builtin_amdgcn_mfma_f32_16x16x32_bf16(ah[mf], bh[nf], acc[mf][nf], 0, 0, 0);
          acc[mf][nf] = __builtin_amdgcn_mfma_f32_16x16x32_bf16(ah[mf], bl[nf], acc[mf][nf], 0, 0, 0);
          acc[mf][nf] = __builtin_amdgcn_mfma_f32_16x16x32_bf16(al[mf], bh[nf], acc[mf][nf], 0, 0, 0);
        }
    }
    __syncthreads();
  }
#pragma unroll
  for (int mf = 0; mf < 4; mf++)
#pragma unroll
    for (int nf = 0; nf < 4; nf++)
#pragma unroll
      for (int j = 0; j < 4; j++) {
        int m = m0 + wm * 64 + mf * 16 + rg * 4 + j;
        int n = n0 + wn * 64 + nf * 16 + c16;
        qkv[(size_t)m * QKVN + n] = acc[mf][nf][j];
      }
}

// ---------------- RoPE q,k -> f16; K written FRAGMENT-MAJOR for the attn kernel ----------------
// kf2[hk][tile64][frag f=(kk*2+hf)*4+dk][lane][e]  (16B per lane per frag)
__global__ __launch_bounds__(256) void k_rope_qk(const float* __restrict__ qkv,
                                                 const float* __restrict__ cosb,
                                                 const float* __restrict__ sinb,
                                                 u16* __restrict__ qf, u16* __restrict__ kf2) {
  int idx = blockIdx.x * 256 + threadIdx.x;  // SQ*24*64
  int i = idx & 63;
  int th = idx >> 6;
  int h = th % 24, t = th / 24;
  int c0 = (h < 16) ? h * 128 + 2 * i : 2048 + (h - 16) * 128 + 2 * i;
  float2 eo = *(const float2*)(qkv + (size_t)t * QKVN + c0);
  float c = cosb[t * 64 + i], s = sinb[t * 64 + i];
  float re = eo.x * c - eo.y * s;
  float ro = eo.x * s + eo.y * c;
  if (h < 16) {
    const float QSC = (float)(1.4426950408889634 * 0.08838834764831843);  // log2e/sqrt(128)
    u32 pk = (u32)f2h(re * QSC) | ((u32)f2h(ro * QSC) << 16);
    *(u32*)(qf + ((size_t)h * SQ + t) * 128 + 2 * i) = pk;
  } else {
    int hk = h - 16;
    int d = 2 * i;
    int tile = t >> 6, tok = t & 63;
    int kk = tok >> 5, t5 = tok & 31;
    int hf = (t5 >> 2) & 1, c16v = ((t5 >> 3) << 2) | (t5 & 3);
    int dk = d >> 5, rg = (d >> 3) & 3, e = d & 7;
    int lane = rg * 16 + c16v, f = (kk * 2 + hf) * 4 + dk;
    u32 pk = (u32)f2h(re) | ((u32)f2h(ro) << 16);
    *(u32*)(kf2 + ((size_t)((hk * 64 + tile) * 16 + f) * 64 + lane) * 8 + e) = pk;
  }
}

// ---------------- block means of roped k (double accumulation) ----------------
__global__ __launch_bounds__(64) void k_bm(const float* __restrict__ qkv,
                                           const float* __restrict__ cosb,
                                           const float* __restrict__ sinb,
                                           float* __restrict__ bm) {
  int hk = blockIdx.x >> 5, n = blockIdx.x & 31;
  int i = threadIdx.x;  // 64 pairs
  double se = 0.0, so = 0.0;
  for (int t = 0; t < 128; t++) {
    int tt = n * 128 + t;
    float2 eo = *(const float2*)(qkv + (size_t)tt * QKVN + 2048 + hk * 128 + 2 * i);
    float c = cosb[tt * 64 + i], s = sinb[tt * 64 + i];
    se += (double)(eo.x * c - eo.y * s);
    so += (double)(eo.x * s + eo.y * c);
  }
  float* o = bm + ((size_t)(hk * 32 + n)) * 128 + 2 * i;
  o[0] = (float)(se * (1.0 / 128.0));
  o[1] = (float)(so * (1.0 / 128.0));
}

// ---------------- gating: own-block in top-8? (only matters for b>=8) ----------------
__global__ __launch_bounds__(64) void k_gate(const float* __restrict__ qkv,
                                             const float* __restrict__ cosb,
                                             const float* __restrict__ sinb,
                                             const float* __restrict__ bm,
                                             unsigned char* __restrict__ sel) {
  __shared__ float q[64][129];
  __shared__ float bml[32 * 128];
  int bz = blockIdx.x;  // h*48 + (b-8)*2 + half
  int h = bz / 48;
  int rem = bz % 48;
  int b = 8 + (rem >> 1);
  int half = rem & 1;
  int tid = threadIdx.x;
  int hk = h >> 1;
  for (int rr = 0; rr < 64; rr++) {
    int ss = b * 128 + half * 64 + rr;
    float2 eo = *(const float2*)(qkv + (size_t)ss * QKVN + h * 128 + 2 * tid);
    float c = cosb[ss * 64 + tid], sn = sinb[ss * 64 + tid];
    q[rr][2 * tid]     = eo.x * c - eo.y * sn;
    q[rr][2 * tid + 1] = eo.x * sn + eo.y * c;
  }
  for (int o = tid; o < (b + 1) * 128; o += 64) bml[o] = bm[(size_t)hk * 32 * 128 + o];
  __syncthreads();
  int s = b * 128 + half * 64 + tid;
  double gb = 0.0;
  for (int d = 0; d < 128; d++) gb += (double)q[tid][d] * (double)bml[b * 128 + d];
  int cnt = 0;
  for (int n = 0; n < b; n++) {
    double g = 0.0;
    for (int d = 0; d < 128; d++) g += (double)q[tid][d] * (double)bml[n * 128 + d];
    cnt += (g >= gb) ? 1 : 0;
  }
  sel[h * SQ + s] = (cnt <= 7) ? 1 : 0;
}

// ---------------- v -> vt2 FRAGMENT-MAJOR f16: vt2[hk][tile64][g=kk*8+nf][lane][e] ----------------
__global__ __launch_bounds__(256) void k_vt2(const float* __restrict__ qkv, u16* __restrict__ vt2) {
  int hk = blockIdx.x & 7, tile = blockIdx.x >> 3;  // 512 blocks
  int tid = threadIdx.x;
  u16* dst = vt2 + (size_t)(hk * 64 + tile) * 8192;
#pragma unroll
  for (int rep = 0; rep < 16; rep++) {
    int idx = rep * 256 + tid;      // 0..4095
    int tp = idx >> 7;              // token pair 0..31
    int d  = idx & 127;
    int t  = tile * 64 + tp * 2;
    float v0 = qkv[(size_t)t * QKVN + 3072 + hk * 128 + d];
    float v1 = qkv[(size_t)(t + 1) * QKVN + 3072 + hk * 128 + d];
    int tok = tp * 2;
    int kk = tok >> 5, rg = (tok >> 3) & 3, e = tok & 7;
    int nf = d >> 4, c16v = d & 15;
    int lane = rg * 16 + c16v, g = kk * 8 + nf;
    u32 pk = (u32)f2h(v0) | ((u32)f2h(v1) << 16);
    *(u32*)(dst + ((size_t)(g * 64 + lane)) * 8 + e) = pk;
  }
}

// ---------------- split-KV flash attention: fragment-major LDS dbuf + register softmax ----------------
// 64-token tiles. Per tile: stage next (gll16, linear), ds_read current (linear, conflict-free),
// swapped QK^T / PV MFMAs, all-register online softmax with defer-max.
__global__ __launch_bounds__(256) void k_attn_chunk(
    const u16* __restrict__ qf, const u16* __restrict__ kf2, const u16* __restrict__ vt2,
    const unsigned char* __restrict__ sel, float* __restrict__ po, float* __restrict__ ml) {
  __shared__ u16 lds[2][16384];    // 2 bufs x (K 16KB | V 16KB) = 64KB
  const int L = blockIdx.x;        // [0,1280): laid out so XCD == hk
  const int hk = L & 7;
  const int c = L >> 3;            // [0,160)
  const int h = hk * 2 + (c & 1);
  const int cc = c >> 1;           // [0,80)
  int qb, chunk;
  if (cc < 8)       { qb = cc;                   chunk = 0; }
  else if (cc < 24) { qb = 8 + ((cc - 8) >> 1);  chunk = (cc - 8) & 1; }
  else if (cc < 48) { qb = 16 + (cc - 24) / 3;   chunk = (cc - 24) % 3; }
  else              { qb = 24 + ((cc - 48) >> 2); chunk = (cc - 48) & 3; }
  const int nt128 = (qb < 8) ? 8 : (qb + 1);
  const int t0 = chunk * 16;                       // 64-token units
  const int t1 = (t0 + 16 < nt128 * 2) ? t0 + 16 : nt128 * 2;
  const int tid = threadIdx.x;
  const int lane = tid & 63, wid = tid >> 6;
  const int rg = lane >> 4, c16 = lane & 15;
  const bool hasMask = (qb >= 8);

  // Q fragments (B-operand of S^T)
  half8 aq[2][4];
#pragma unroll
  for (int mi = 0; mi < 2; mi++)
#pragma unroll
    for (int dk = 0; dk < 4; dk++) {
      int srow = qb * 128 + wid * 32 + mi * 16 + c16;
      aq[mi][dk] = *(const half8*)(qf + ((size_t)h * SQ + srow) * 128 + dk * 32 + rg * 8);
    }

  bool os2[2] = {true, true};
  if (hasMask) {
#pragma unroll
    for (int mi = 0; mi < 2; mi++)
      os2[mi] = sel[h * SQ + qb * 128 + wid * 32 + mi * 16 + c16] != 0;
  }

  f32x4 accO[2][8];
#pragma unroll
  for (int mi = 0; mi < 2; mi++)
#pragma unroll
    for (int nf = 0; nf < 8; nf++) accO[mi][nf] = (f32x4){0.f, 0.f, 0.f, 0.f};
  float mrun[2] = {-1e30f, -1e30f}, lrun[2] = {0.f, 0.f};

  const u16* kbase = kf2 + (size_t)hk * 64 * 8192;
  const u16* vbase = vt2 + (size_t)hk * 64 * 8192;

  auto stage = [&](int b, int n) {
    const u16* ks = kbase + (size_t)n * 8192;
    const u16* vs = vbase + (size_t)n * 8192;
#pragma unroll
    for (int r = 0; r < 4; r++)
      gll16(ks + r * 2048 + wid * 512 + lane * 8, &lds[b][r * 2048 + wid * 512]);
#pragma unroll
    for (int r = 0; r < 4; r++)
      gll16(vs + r * 2048 + wid * 512 + lane * 8, &lds[b][8192 + r * 2048 + wid * 512]);
  };

  stage(0, t0);

  for (int n = t0; n < t1; n++) {
    const int cur = (n - t0) & 1;
    __syncthreads();                 // drains vmcnt/lgkmcnt: staged tile ready, prev buf free
    if (n + 1 < t1) stage(cur ^ 1, n + 1);
    const u16* lb = &lds[cur][0];

    // QK^T (swapped): A = K fragments (linear ds_read), B = Q
    f32x4 st[2][2][2];
#pragma unroll
    for (int kk = 0; kk < 2; kk++)
#pragma unroll
      for (int hf = 0; hf < 2; hf++)
#pragma unroll
        for (int mi = 0; mi < 2; mi++) st[kk][hf][mi] = (f32x4){0.f, 0.f, 0.f, 0.f};

    __builtin_amdgcn_s_setprio(1);
#pragma unroll
    for (int kk = 0; kk < 2; kk++)
#pragma unroll
      for (int hf = 0; hf < 2; hf++) {
        half8 ka[4];
#pragma unroll
        for (int dk = 0; dk < 4; dk++)
          ka[dk] = *(const half8*)(lb + ((kk * 2 + hf) * 4 + dk) * 512 + lane * 8);
#pragma unroll
        for (int dk = 0; dk < 4; dk++) {
          st[kk][hf][0] = __builtin_amdgcn_mfma_f32_16x16x32_f16(ka[dk], aq[0][dk], st[kk][hf][0], 0, 0, 0);
          st[kk][hf][1] = __builtin_amdgcn_mfma_f32_16x16x32_f16(ka[dk], aq[1][dk], st[kk][hf][1], 0, 0, 0);
        }
      }
    __builtin_amdgcn_s_setprio(0);

    // mask (only last two 64-tiles of own block, when own block unselected)
    if (hasMask && n >= 2 * qb) {
#pragma unroll
      for (int mi = 0; mi < 2; mi++) {
        if (!os2[mi]) {
          int row = qb * 128 + wid * 32 + mi * 16 + c16;
#pragma unroll
          for (int kk = 0; kk < 2; kk++)
#pragma unroll
            for (int hf = 0; hf < 2; hf++)
#pragma unroll
              for (int j = 0; j < 4; j++) {
                int tg = n * 64 + kk * 32 + rg * 8 + hf * 4 + j;
                if (tg > row) st[kk][hf][mi][j] = -1e30f;
              }
        }
      }
    }

    // online softmax, per-lane rows, defer-max (THR=8 in log2 units)
#pragma unroll
    for (int mi = 0; mi < 2; mi++) {
      float mt = st[0][0][mi][0];
#pragma unroll
      for (int kk = 0; kk < 2; kk++)
#pragma unroll
        for (int hf = 0; hf < 2; hf++)
#pragma unroll
          for (int j = 0; j < 4; j++)
            if (kk | hf | j) mt = fmaxf(mt, st[kk][hf][mi][j]);
      mt = fmaxf(mt, __shfl_xor(mt, 16, 64));
      mt = fmaxf(mt, __shfl_xor(mt, 32, 64));
      if (!__all(mt <= mrun[mi] + 8.f)) {
        float mnew = fmaxf(mrun[mi], mt);
        float sc = exp2f(mrun[mi] - mnew);
        mrun[mi] = mnew;
        lrun[mi] *= sc;
#pragma unroll
        for (int nf = 0; nf < 8; nf++) accO[mi][nf] *= sc;
      }
      float ps = 0.f;
#pragma unroll
      for (int kk = 0; kk < 2; kk++)
#pragma unroll
        for (int hf = 0; hf < 2; hf++)
#pragma unroll
          for (int j = 0; j < 4; j++) {
            float p = exp2f(st[kk][hf][mi][j] - mrun[mi]);
            st[kk][hf][mi][j] = p;
            ps += p;
          }
      ps += __shfl_xor(ps, 16, 64);
      ps += __shfl_xor(ps, 32, 64);
      lrun[mi] += ps;
    }

    // pack P^T fragments (e = hf*4+j)
    half8 pa[2][2];
#pragma unroll
    for (int kk = 0; kk < 2; kk++)
#pragma unroll
      for (int mi = 0; mi < 2; mi++) {
        union { half8 v; _Float16 e[8]; } pu;
#pragma unroll
        for (int hf = 0; hf < 2; hf++)
#pragma unroll
          for (int j = 0; j < 4; j++)
            pu.e[hf * 4 + j] = (_Float16)st[kk][hf][mi][j];
        pa[kk][mi] = pu.v;
      }

    // PV (swapped): A = V^T fragments (linear ds_read), B = P^T
    __builtin_amdgcn_s_setprio(1);
#pragma unroll
    for (int kk = 0; kk < 2; kk++)
#pragma unroll
      for (int nf = 0; nf < 8; nf++) {
        half8 va = *(const half8*)(lb + 8192 + (kk * 8 + nf) * 512 + lane * 8);
        accO[0][nf] = __builtin_amdgcn_mfma_f32_16x16x32_f16(va, pa[kk][0], accO[0][nf], 0, 0, 0);
        accO[1][nf] = __builtin_amdgcn_mfma_f32_16x16x32_f16(va, pa[kk][1], accO[1][nf], 0, 0, 0);
      }
    __builtin_amdgcn_s_setprio(0);
  }

  // write partials (unnormalized O^T laid back row-major + per-row m,l)
  const int pidx = h * 80 + cidx(qb) + chunk;
  float* pob = po + (size_t)pidx * 16384;
#pragma unroll
  for (int mi = 0; mi < 2; mi++) {
    int row = wid * 32 + mi * 16 + c16;
#pragma unroll
    for (int nf = 0; nf < 8; nf++)
      *(f32x4*)&pob[row * 128 + nf * 16 + rg * 4] = accO[mi][nf];
  }
  if (rg == 0) {
#pragma unroll
    for (int mi = 0; mi < 2; mi++) {
      int row = wid * 32 + mi * 16 + c16;
      ml[(size_t)pidx * 256 + row * 2]     = mrun[mi];
      ml[(size_t)pidx * 256 + row * 2 + 1] = lrun[mi];
    }
  }
}

// ---------------- combine split-KV partials -> attn (f16) ----------------
__global__ __launch_bounds__(256) void k_attn_combine(
    const float* __restrict__ po, const float* __restrict__ ml, u16* __restrict__ attn) {
  const int qb = blockIdx.x, h = blockIdx.y;
  const int nc = (qb < 8) ? 1 : (qb < 16) ? 2 : (qb < 24) ? 3 : 4;
  const int base = h * 80 + cidx(qb);
  const int tid = threadIdx.x;
  const int r = tid >> 1, h64 = (tid & 1) * 64;
  float m[4], l[4], M = -1e30f;
#pragma unroll
  for (int ci = 0; ci < 4; ci++) {
    if (ci < nc) {
      m[ci] = ml[(size_t)(base + ci) * 256 + r * 2];
      l[ci] = ml[(size_t)(base + ci) * 256 + r * 2 + 1];
    } else { m[ci] = -1e30f; l[ci] = 0.f; }
    M = fmaxf(M, m[ci]);
  }
  float w[4], Ls = 0.f;
#pragma unroll
  for (int ci = 0; ci < 4; ci++) { w[ci] = exp2f(m[ci] - M); Ls += w[ci] * l[ci]; }
  float inv = 1.0f / Ls;
  for (int d = 0; d < 64; d += 4) {
    float4 a = make_float4(0.f, 0.f, 0.f, 0.f);
#pragma unroll
    for (int ci = 0; ci < 4; ci++) {
      if (ci < nc) {
        const float4 v = *(const float4*)&po[(size_t)(base + ci) * 16384 + r * 128 + h64 + d];
        a.x += w[ci] * v.x; a.y += w[ci] * v.y; a.z += w[ci] * v.z; a.w += w[ci] * v.w;
      }
    }
    u32 p0 = (u32)f2h(a.x * inv) | ((u32)f2h(a.y * inv) << 16);
    u32 p1 = (u32)f2h(a.z * inv) | ((u32)f2h(a.w * inv) << 16);
    *(uint2*)&attn[(size_t)(qb * 128 + r) * DIMM + h * 128 + h64 + d] = make_uint2(p0, p1);
  }
}

// ---------------- out = attn @ wo (f16 GEMM, fp32 out) ----------------
__global__ __launch_bounds__(256) void k_gemm_out(
    const u16* __restrict__ attn, const u16* __restrict__ wot, float* __restrict__ out) {
  __shared__ u16 lds[2 * 128 * 64];  // A | B, 32KB
  const int tid = threadIdx.x;
  const int lane = tid & 63, wid = tid >> 6;
  const int rg = lane >> 4, c16 = lane & 15;
  const int m0 = blockIdx.y * 128, n0 = blockIdx.x * 128;
  const int wm = wid >> 1, wn = wid & 1;
  const u16* gsrc = (wid < 2) ? attn + (size_t)m0 * 2048 : wot + (size_t)n0 * 2048;
  const int sr = lane >> 3, scn = lane & 7;

  f32x4 acc[4][4];
#pragma unroll
  for (int a = 0; a < 4; a++)
#pragma unroll
    for (int b = 0; b < 4; b++) acc[a][b] = (f32x4){0.f, 0.f, 0.f, 0.f};

  for (int k0 = 0; k0 < 2048; k0 += 64) {
#pragma unroll
    for (int i = 0; i < 8; i++) {
      int slot = wid * 8 + i;
      int s2 = slot & 15;
      int r = s2 * 8 + sr;
      int cs = (scn ^ (r & 7)) * 8;
      gll16(gsrc + (size_t)r * 2048 + k0 + cs, lds + slot * 512);
    }
    __syncthreads();
#pragma unroll
    for (int kk = 0; kk < 2; kk++) {
      half8 a[4], b[4];
      int ch = kk * 4 + rg;
#pragma unroll
      for (int mf = 0; mf < 4; mf++) {
        int m = wm * 64 + mf * 16 + c16;
        a[mf] = *(const half8*)(lds + m * 64 + ((ch ^ (m & 7)) * 8));
      }
#pragma unroll
      for (int nf = 0; nf < 4; nf++) {
        int n = wn * 64 + nf * 16 + c16;
        b[nf] = *(const half8*)(lds + 8192 + n * 64 + ((ch ^ (n & 7)) * 8));
      }
#pragma unroll
      for (int mf = 0; mf < 4; mf++)
#pragma unroll
        for (int nf = 0; nf < 4; nf++)
          acc[mf][nf] = __builtin_amdgcn_mfma_f32_16x16x32_f16(a[mf], b[nf], acc[mf][nf], 0, 0, 0);
    }
    __syncthreads();
  }
#pragma unroll
  for (int mf = 0; mf < 4; mf++)
#pragma unroll
    for (int nf = 0; nf < 4; nf++)
#pragma unroll
      for (int j = 0; j < 4; j++) {
        int m = m0 + wm * 64 + mf * 16 + rg * 4 + j;
        int n = n0 + wn * 64 + nf * 16 + c16;
        out[(size_t)m * DIMM + n] = acc[mf][nf][j];
      }
}

extern "C" void kernel_launch(void* const* d_in, const int* in_sizes, int n_in,
                              void* d_out, int out_size, void* d_ws, size_t ws_size,
                              hipStream_t stream) {
  (void)in_sizes; (void)n_in; (void)out_size; (void)ws_size;
  const float* x  = (const float*)d_in[0];
  const float* wq = (const float*)d_in[1];
  const float* wk = (const float*)d_in[2];
  const float* wv = (const float*)d_in[3];
  const float* wo = (const float*)d_in[4];
  float* out = (float*)d_out;

  char* ws = (char*)d_ws;
  const size_t MB = 1024 * 1024;
  // Region A (128MB): xh|xl|wth|wtl|qkv during projection; aliased by po|ml for split-KV
  char* A = ws;
  u16*   xh  = (u16*)(A);
  u16*   xl  = (u16*)(A + 16 * MB);
  u16*   wth = (u16*)(A + 32 * MB);
  u16*   wtl = (u16*)(A + 48 * MB);
  float* qkv = (float*)(A + 64 * MB);
  float* po  = (float*)(A);            // 80MB (1280 x 128 x 128 f32), overlays dead buffers
  float* ml  = (float*)(A + 88 * MB);  // 1.25MB, inside dead qkv region
  // Region B (persistent)
  char* B = ws + 128 * MB;
  size_t off = 0;
  auto alloc = [&](size_t b) { char* p = B + off; off += (b + 255) & ~(size_t)255; return p; };
  u16*   wot  = (u16*)alloc((size_t)DIMM * DIMM * 2);
  float* cosb = (float*)alloc((size_t)SQ * 64 * 4);
  float* sinb = (float*)alloc((size_t)SQ * 64 * 4);
  u16*   qf   = (u16*)alloc((size_t)16 * SQ * 128 * 2);
  u16*   kf2  = (u16*)alloc((size_t)8 * SQ * 128 * 2);
  u16*   vt2  = (u16*)alloc((size_t)8 * 128 * SQ * 2);
  float* bm   = (float*)alloc((size_t)8 * 32 * 128 * 4);
  unsigned char* sel = (unsigned char*)alloc((size_t)16 * SQ);
  u16*   attn = (u16*)alloc((size_t)SQ * DIMM * 2);

  k_tables<<<SQ * 64 / 256, 256, 0, stream>>>(cosb, sinb);
  k_split_x<<<(SQ * DIMM) / (256 * 4), 256, 0, stream>>>(x, xh, xl);
  k_trans_split<<<dim3(32, 32), 256, 0, stream>>>(wq, 2048, wth, wtl, 0);
  k_trans_split<<<dim3(16, 32), 256, 0, stream>>>(wk, 1024, wth, wtl, 2048);
  k_trans_split<<<dim3(16, 32), 256, 0, stream>>>(wv, 1024, wth, wtl, 3072);
  k_trans_f16<<<dim3(32, 32), 256, 0, stream>>>(wo, 2048, wot);
  k_gemm_qkv<<<dim3(32, 32), 256, 0, stream>>>(xh, xl, wth, wtl, qkv);
  k_rope_qk<<<(SQ * 24 * 64) / 256, 256, 0, stream>>>(qkv, cosb, sinb, qf, kf2);
  k_vt2<<<512, 256, 0, stream>>>(qkv, vt2);
  k_bm<<<256, 64, 0, stream>>>(qkv, cosb, sinb, bm);
  k_gate<<<16 * 48, 64, 0, stream>>>(qkv, cosb, sinb, bm, sel);
  // qkv (and xh/xl/wth/wtl) are dead past this point -> po/ml alias them
  k_attn_chunk<<<1280, 256, 0, stream>>>(qf, kf2, vt2, sel, po, ml);
  k_attn_combine<<<dim3(32, 16), 256, 0, stream>>>(po, ml, attn);
  k_gemm_out<<<dim3(16, 32), 256, 0, stream>>>(attn, wot, out);
}

// Round 5
// 568.644 us; speedup vs baseline: 1.5225x; 1.0778x over previous
//
#include <hip/hip_runtime.h>
#include <hip/hip_fp16.h>

#define SQ   4096
#define DIMM 2048
#define QKVN 4096   // 2048 q | 1024 k | 1024 v

typedef unsigned short u16;
typedef unsigned int u32;
typedef __attribute__((ext_vector_type(8))) short    short8;  // bf16x8 frag
typedef __attribute__((ext_vector_type(8))) _Float16 half8;   // f16x8 frag
typedef __attribute__((ext_vector_type(4))) float    f32x4;

__device__ __forceinline__ u16 f2bf(float f) {
  u32 u = __float_as_uint(f);
  u32 r = u + 0x7fffu + ((u >> 16) & 1u);
  return (u16)(r >> 16);
}
__device__ __forceinline__ float bf2f(u16 h) { return __uint_as_float(((u32)h) << 16); }
__device__ __forceinline__ u16 f2h(float f) { return __half_as_ushort(__float2half(f)); }
__device__ __forceinline__ float h2f(u16 h) { union { u16 u; _Float16 f; } c; c.u = h; return (float)c.f; }

__device__ __forceinline__ void gll16(const void* g, void* l) {
  __builtin_amdgcn_global_load_lds((const __attribute__((address_space(1))) void*)g,
                                   (__attribute__((address_space(3))) void*)l, 16, 0, 0);
}

// chunk-slot cumulative index per head: chunks of 8 KV blocks (128-token units)
__device__ __host__ __forceinline__ int cidx(int qb) {
  return qb < 8 ? qb : qb < 16 ? 8 + (qb - 8) * 2 : qb < 24 ? 24 + (qb - 16) * 3 : 48 + (qb - 24) * 4;
}

// ---------------- RoPE tables (double-accurate, rounded to fp32) ----------------
__global__ __launch_bounds__(256) void k_tables(float* __restrict__ cosb, float* __restrict__ sinb) {
  int idx = blockIdx.x * 256 + threadIdx.x;  // SQ*64
  int pos = idx >> 6, i = idx & 63;
  double f = 1.0 / pow(10000.0, (double)i / 64.0);
  float inv = (float)f;
  float ang = (float)pos * inv;
  cosb[idx] = (float)cos((double)ang);
  sinb[idx] = (float)sin((double)ang);
}

// ---------------- split x into bf16 hi/lo ----------------
__global__ __launch_bounds__(256) void k_split_x(const float* __restrict__ x,
                                                 u16* __restrict__ xh, u16* __restrict__ xl) {
  size_t base = ((size_t)blockIdx.x * 256 + threadIdx.x) * 4;
  float4 v = *(const float4*)(x + base);
  float vv[4] = {v.x, v.y, v.z, v.w};
  u16 hh[4], ll[4];
#pragma unroll
  for (int j = 0; j < 4; j++) {
    hh[j] = f2bf(vv[j]);
    ll[j] = f2bf(vv[j] - bf2f(hh[j]));
  }
  *(uint2*)(xh + base) = make_uint2((u32)hh[0] | ((u32)hh[1] << 16), (u32)hh[2] | ((u32)hh[3] << 16));
  *(uint2*)(xl + base) = make_uint2((u32)ll[0] | ((u32)ll[1] << 16), (u32)ll[2] | ((u32)ll[3] << 16));
}

// ---------------- transpose W (KxN) -> WT (NxK) with bf16 hi/lo split ----------------
__global__ __launch_bounds__(256) void k_trans_split(const float* __restrict__ src, int N,
                                                     u16* __restrict__ dh, u16* __restrict__ dl,
                                                     int rowOff) {
  __shared__ float t[64][65];
  int n0 = blockIdx.x * 64, k0 = blockIdx.y * 64;
  int tid = threadIdx.x;
  int c = tid & 63, r4 = tid >> 6;
#pragma unroll
  for (int it = 0; it < 16; it++) {
    int kk = it * 4 + r4;
    t[kk][c] = src[(size_t)(k0 + kk) * N + n0 + c];
  }
  __syncthreads();
#pragma unroll
  for (int it = 0; it < 16; it++) {
    int nn = it * 4 + r4;
    float v = t[c][nn];
    u16 hh = f2bf(v);
    size_t o = (size_t)(rowOff + n0 + nn) * 2048 + k0 + c;
    dh[o] = hh;
    dl[o] = f2bf(v - bf2f(hh));
  }
}

// ---------------- transpose wo (KxN fp32) -> woT (NxK f16) ----------------
__global__ __launch_bounds__(256) void k_trans_f16(const float* __restrict__ src, int N,
                                                   u16* __restrict__ dst) {
  __shared__ float t[64][65];
  int n0 = blockIdx.x * 64, k0 = blockIdx.y * 64;
  int tid = threadIdx.x;
  int c = tid & 63, r4 = tid >> 6;
#pragma unroll
  for (int it = 0; it < 16; it++) {
    int kk = it * 4 + r4;
    t[kk][c] = src[(size_t)(k0 + kk) * N + n0 + c];
  }
  __syncthreads();
#pragma unroll
  for (int it = 0; it < 16; it++) {
    int nn = it * 4 + r4;
    dst[(size_t)(n0 + nn) * 2048 + k0 + c] = f2h(t[c][nn]);
  }
}

// ---------------- QKV projection: bf16x3 split GEMM, 128x128 tile, BK=64, XCD-swizzled ----------------
__global__ __launch_bounds__(256) void k_gemm_qkv(
    const u16* __restrict__ xh, const u16* __restrict__ xl,
    const u16* __restrict__ wth, const u16* __restrict__ wtl,
    float* __restrict__ qkv) {
  __shared__ u16 lds[4 * 128 * 64];  // Ah | Al | Bh | Bl, 64KB
  const int tid = threadIdx.x;
  const int lane = tid & 63, wid = tid >> 6;
  const int rg = lane >> 4, c16 = lane & 15;
  const int bid0 = blockIdx.y * 32 + blockIdx.x;           // 1024 blocks
  const int swz = (bid0 & 7) * 128 + (bid0 >> 3);          // bijective XCD chunking
  const int m0 = (swz >> 5) * 128, n0 = (swz & 31) * 128;
  const int wm = wid >> 1, wn = wid & 1;
  const u16* gsrc = (wid == 0) ? xh + (size_t)m0 * 2048
                  : (wid == 1) ? xl + (size_t)m0 * 2048
                  : (wid == 2) ? wth + (size_t)n0 * 2048
                               : wtl + (size_t)n0 * 2048;
  u16* ldsm = lds + wid * 8192;
  const int sr = lane >> 3, scn = lane & 7;

  f32x4 acc[4][4];
#pragma unroll
  for (int a = 0; a < 4; a++)
#pragma unroll
    for (int b = 0; b < 4; b++) acc[a][b] = (f32x4){0.f, 0.f, 0.f, 0.f};

  for (int k0 = 0; k0 < 2048; k0 += 64) {
#pragma unroll
    for (int i = 0; i < 16; i++) {
      int r = i * 8 + sr;
      int cs = (scn ^ (r & 7)) * 8;
      gll16(gsrc + (size_t)r * 2048 + k0 + cs, ldsm + i * 512);
    }
    __syncthreads();
#pragma unroll
    for (int kk = 0; kk < 2; kk++) {
      short8 ah[4], al[4], bh[4], bl[4];
      int ch = kk * 4 + rg;
#pragma unroll
      for (int mf = 0; mf < 4; mf++) {
        int m = wm * 64 + mf * 16 + c16;
        int off = m * 64 + ((ch ^ (m & 7)) * 8);
        ah[mf] = *(const short8*)(lds + off);
        al[mf] = *(const short8*)(lds + 8192 + off);
      }
#pragma unroll
      for (int nf = 0; nf < 4; nf++) {
        int n = wn * 64 + nf * 16 + c16;
        int off = n * 64 + ((ch ^ (n & 7)) * 8);
        bh[nf] = *(const short8*)(lds + 16384 + off);
        bl[nf] = *(const short8*)(lds + 24576 + off);
      }
#pragma unroll
      for (int mf = 0; mf < 4; mf++)
#pragma unroll
        for (int nf = 0; nf < 4; nf++) {
          acc[mf][nf] = __builtin_amdgcn_mfma_f32_16x16x32_bf16(ah[mf], bh[nf], acc[mf][nf], 0, 0, 0);
          acc[mf][nf] = __builtin_amdgcn_mfma_f32_16x16x32_bf16(ah[mf], bl[nf], acc[mf][nf], 0, 0, 0);
          acc[mf][nf] = __builtin_amdgcn_mfma_f32_16x16x32_bf16(al[mf], bh[nf], acc[mf][nf], 0, 0, 0);
        }
    }
    __syncthreads();
  }
#pragma unroll
  for (int mf = 0; mf < 4; mf++)
#pragma unroll
    for (int nf = 0; nf < 4; nf++)
#pragma unroll
      for (int j = 0; j < 4; j++) {
        int m = m0 + wm * 64 + mf * 16 + rg * 4 + j;
        int n = n0 + wn * 64 + nf * 16 + c16;
        qkv[(size_t)m * QKVN + n] = acc[mf][nf][j];
      }
}

// ---------------- RoPE q,k -> f16; K written FRAGMENT-MAJOR for the attn kernel ----------------
// kf2[hk][tile64][frag f=(kk*2+hf)*4+dk][lane][e]  (16B per lane per frag)
__global__ __launch_bounds__(256) void k_rope_qk(const float* __restrict__ qkv,
                                                 const float* __restrict__ cosb,
                                                 const float* __restrict__ sinb,
                                                 u16* __restrict__ qf, u16* __restrict__ kf2) {
  int idx = blockIdx.x * 256 + threadIdx.x;  // SQ*24*64
  int i = idx & 63;
  int th = idx >> 6;
  int h = th % 24, t = th / 24;
  int c0 = (h < 16) ? h * 128 + 2 * i : 2048 + (h - 16) * 128 + 2 * i;
  float2 eo = *(const float2*)(qkv + (size_t)t * QKVN + c0);
  float c = cosb[t * 64 + i], s = sinb[t * 64 + i];
  float re = eo.x * c - eo.y * s;
  float ro = eo.x * s + eo.y * c;
  if (h < 16) {
    const float QSC = (float)(1.4426950408889634 * 0.08838834764831843);  // log2e/sqrt(128)
    u32 pk = (u32)f2h(re * QSC) | ((u32)f2h(ro * QSC) << 16);
    *(u32*)(qf + ((size_t)h * SQ + t) * 128 + 2 * i) = pk;
  } else {
    int hk = h - 16;
    int d = 2 * i;
    int tile = t >> 6, tok = t & 63;
    int kk = tok >> 5, t5 = tok & 31;
    int hf = (t5 >> 2) & 1, c16v = ((t5 >> 3) << 2) | (t5 & 3);
    int dk = d >> 5, rg = (d >> 3) & 3, e = d & 7;
    int lane = rg * 16 + c16v, f = (kk * 2 + hf) * 4 + dk;
    u32 pk = (u32)f2h(re) | ((u32)f2h(ro) << 16);
    *(u32*)(kf2 + ((size_t)((hk * 64 + tile) * 16 + f) * 64 + lane) * 8 + e) = pk;
  }
}

// ---------------- block means of roped k (double accumulation) ----------------
__global__ __launch_bounds__(64) void k_bm(const float* __restrict__ qkv,
                                           const float* __restrict__ cosb,
                                           const float* __restrict__ sinb,
                                           float* __restrict__ bm) {
  int hk = blockIdx.x >> 5, n = blockIdx.x & 31;
  int i = threadIdx.x;  // 64 pairs
  double se = 0.0, so = 0.0;
  for (int t = 0; t < 128; t++) {
    int tt = n * 128 + t;
    float2 eo = *(const float2*)(qkv + (size_t)tt * QKVN + 2048 + hk * 128 + 2 * i);
    float c = cosb[tt * 64 + i], s = sinb[tt * 64 + i];
    se += (double)(eo.x * c - eo.y * s);
    so += (double)(eo.x * s + eo.y * c);
  }
  float* o = bm + ((size_t)(hk * 32 + n)) * 128 + 2 * i;
  o[0] = (float)(se * (1.0 / 128.0));
  o[1] = (float)(so * (1.0 / 128.0));
}

// ---------------- gating: own-block in top-8? (only matters for b>=8) ----------------
__global__ __launch_bounds__(64) void k_gate(const float* __restrict__ qkv,
                                             const float* __restrict__ cosb,
                                             const float* __restrict__ sinb,
                                             const float* __restrict__ bm,
                                             unsigned char* __restrict__ sel) {
  __shared__ float q[64][129];
  __shared__ float bml[32 * 128];
  int bz = blockIdx.x;  // h*48 + (b-8)*2 + half
  int h = bz / 48;
  int rem = bz % 48;
  int b = 8 + (rem >> 1);
  int half = rem & 1;
  int tid = threadIdx.x;
  int hk = h >> 1;
  for (int rr = 0; rr < 64; rr++) {
    int ss = b * 128 + half * 64 + rr;
    float2 eo = *(const float2*)(qkv + (size_t)ss * QKVN + h * 128 + 2 * tid);
    float c = cosb[ss * 64 + tid], sn = sinb[ss * 64 + tid];
    q[rr][2 * tid]     = eo.x * c - eo.y * sn;
    q[rr][2 * tid + 1] = eo.x * sn + eo.y * c;
  }
  for (int o = tid; o < (b + 1) * 128; o += 64) bml[o] = bm[(size_t)hk * 32 * 128 + o];
  __syncthreads();
  int s = b * 128 + half * 64 + tid;
  double gb = 0.0;
  for (int d = 0; d < 128; d++) gb += (double)q[tid][d] * (double)bml[b * 128 + d];
  int cnt = 0;
  for (int n = 0; n < b; n++) {
    double g = 0.0;
    for (int d = 0; d < 128; d++) g += (double)q[tid][d] * (double)bml[n * 128 + d];
    cnt += (g >= gb) ? 1 : 0;
  }
  sel[h * SQ + s] = (cnt <= 7) ? 1 : 0;
}

// ---------------- v -> vt2 FRAGMENT-MAJOR f16: vt2[hk][tile64][g=kk*8+nf][lane][e] ----------------
__global__ __launch_bounds__(256) void k_vt2(const float* __restrict__ qkv, u16* __restrict__ vt2) {
  int hk = blockIdx.x & 7, tile = blockIdx.x >> 3;  // 512 blocks
  int tid = threadIdx.x;
  u16* dst = vt2 + (size_t)(hk * 64 + tile) * 8192;
#pragma unroll
  for (int rep = 0; rep < 16; rep++) {
    int idx = rep * 256 + tid;      // 0..4095
    int tp = idx >> 7;              // token pair 0..31
    int d  = idx & 127;
    int t  = tile * 64 + tp * 2;
    float v0 = qkv[(size_t)t * QKVN + 3072 + hk * 128 + d];
    float v1 = qkv[(size_t)(t + 1) * QKVN + 3072 + hk * 128 + d];
    int tok = tp * 2;
    int kk = tok >> 5, rg = (tok >> 3) & 3, e = tok & 7;
    int nf = d >> 4, c16v = d & 15;
    int lane = rg * 16 + c16v, g = kk * 8 + nf;
    u32 pk = (u32)f2h(v0) | ((u32)f2h(v1) << 16);
    *(u32*)(dst + ((size_t)(g * 64 + lane)) * 8 + e) = pk;
  }
}

// ---------------- split-KV flash attention: KVBLK=32, fragment-major LDS dbuf ----------------
// 32-token tiles, 2x16KB double buffer (32KB LDS -> 3-4 blocks/CU).
// Swapped-operand MFMA, all-register online softmax with defer-max.
// Partials stored NORMALIZED: A = accO/l (f16), m' = m + log2(l) (fp32/row).
__global__ __launch_bounds__(256) void k_attn_chunk(
    const u16* __restrict__ qf, const u16* __restrict__ kf2, const u16* __restrict__ vt2,
    const unsigned char* __restrict__ sel, u16* __restrict__ po, float* __restrict__ ml) {
  __shared__ u16 lds[2][8192];     // 2 bufs x (K 8KB | V 8KB) = 32KB
  const int L = blockIdx.x;        // [0,1280): laid out so XCD == hk
  const int hk = L & 7;
  const int c = L >> 3;            // [0,160)
  const int h = hk * 2 + (c & 1);
  const int cc = c >> 1;           // [0,80)
  int qb, chunk;
  if (cc < 8)       { qb = cc;                   chunk = 0; }
  else if (cc < 24) { qb = 8 + ((cc - 8) >> 1);  chunk = (cc - 8) & 1; }
  else if (cc < 48) { qb = 16 + (cc - 24) / 3;   chunk = (cc - 24) % 3; }
  else              { qb = 24 + ((cc - 48) >> 2); chunk = (cc - 48) & 3; }
  const int nt128 = (qb < 8) ? 8 : (qb + 1);
  const int t0 = chunk * 32;                       // 32-token units
  const int t1 = (t0 + 32 < nt128 * 4) ? t0 + 32 : nt128 * 4;
  const int tid = threadIdx.x;
  const int lane = tid & 63, wid = tid >> 6;
  const int rg = lane >> 4, c16 = lane & 15;
  const bool hasMask = (qb >= 8);

  // Q fragments (B-operand of S^T)
  half8 aq[2][4];
#pragma unroll
  for (int mi = 0; mi < 2; mi++)
#pragma unroll
    for (int dk = 0; dk < 4; dk++) {
      int srow = qb * 128 + wid * 32 + mi * 16 + c16;
      aq[mi][dk] = *(const half8*)(qf + ((size_t)h * SQ + srow) * 128 + dk * 32 + rg * 8);
    }

  bool os2[2] = {true, true};
  if (hasMask) {
#pragma unroll
    for (int mi = 0; mi < 2; mi++)
      os2[mi] = sel[h * SQ + qb * 128 + wid * 32 + mi * 16 + c16] != 0;
  }

  f32x4 accO[2][8];
#pragma unroll
  for (int mi = 0; mi < 2; mi++)
#pragma unroll
    for (int nf = 0; nf < 8; nf++) accO[mi][nf] = (f32x4){0.f, 0.f, 0.f, 0.f};
  float mrun[2] = {-1e30f, -1e30f}, lrun[2] = {0.f, 0.f};

  const u16* kbase = kf2 + (size_t)hk * 64 * 8192;   // 32-tile n at offset n*4096
  const u16* vbase = vt2 + (size_t)hk * 64 * 8192;

  auto stage = [&](int b, int n) {
    const u16* ks = kbase + (size_t)n * 4096;
    const u16* vs = vbase + (size_t)n * 4096;
#pragma unroll
    for (int r = 0; r < 2; r++) {
      gll16(ks + r * 2048 + wid * 512 + lane * 8, &lds[b][r * 2048 + wid * 512]);
      gll16(vs + r * 2048 + wid * 512 + lane * 8, &lds[b][4096 + r * 2048 + wid * 512]);
    }
  };

  stage(0, t0);

  for (int n = t0; n < t1; n++) {
    const int cur = (n - t0) & 1;
    __syncthreads();                 // staged tile ready, prev buf free
    if (n + 1 < t1) stage(cur ^ 1, n + 1);
    const u16* lb = &lds[cur][0];

    // QK^T (swapped): A = K fragments (linear ds_read), B = Q
    f32x4 st[2][2];                  // [hf][mi]
#pragma unroll
    for (int hf = 0; hf < 2; hf++)
#pragma unroll
      for (int mi = 0; mi < 2; mi++) st[hf][mi] = (f32x4){0.f, 0.f, 0.f, 0.f};

    __builtin_amdgcn_s_setprio(1);
#pragma unroll
    for (int hf = 0; hf < 2; hf++) {
      half8 ka[4];
#pragma unroll
      for (int dk = 0; dk < 4; dk++)
        ka[dk] = *(const half8*)(lb + (hf * 4 + dk) * 512 + lane * 8);
#pragma unroll
      for (int dk = 0; dk < 4; dk++) {
        st[hf][0] = __builtin_amdgcn_mfma_f32_16x16x32_f16(ka[dk], aq[0][dk], st[hf][0], 0, 0, 0);
        st[hf][1] = __builtin_amdgcn_mfma_f32_16x16x32_f16(ka[dk], aq[1][dk], st[hf][1], 0, 0, 0);
      }
    }
    __builtin_amdgcn_s_setprio(0);

    // mask (own-block tiles only, when own block unselected)
    if (hasMask && n >= 4 * qb) {
#pragma unroll
      for (int mi = 0; mi < 2; mi++) {
        if (!os2[mi]) {
          int row = qb * 128 + wid * 32 + mi * 16 + c16;
#pragma unroll
          for (int hf = 0; hf < 2; hf++)
#pragma unroll
            for (int j = 0; j < 4; j++) {
              int tg = n * 32 + rg * 8 + hf * 4 + j;
              if (tg > row) st[hf][mi][j] = -1e30f;
            }
        }
      }
    }

    // online softmax, per-lane rows, defer-max (THR=8 in log2 units)
#pragma unroll
    for (int mi = 0; mi < 2; mi++) {
      float mt = st[0][mi][0];
#pragma unroll
      for (int hf = 0; hf < 2; hf++)
#pragma unroll
        for (int j = 0; j < 4; j++)
          if (hf | j) mt = fmaxf(mt, st[hf][mi][j]);
      mt = fmaxf(mt, __shfl_xor(mt, 16, 64));
      mt = fmaxf(mt, __shfl_xor(mt, 32, 64));
      if (!__all(mt <= mrun[mi] + 8.f)) {
        float mnew = fmaxf(mrun[mi], mt);
        float sc = exp2f(mrun[mi] - mnew);
        mrun[mi] = mnew;
        lrun[mi] *= sc;
#pragma unroll
        for (int nf = 0; nf < 8; nf++) accO[mi][nf] *= sc;
      }
      float ps = 0.f;
#pragma unroll
      for (int hf = 0; hf < 2; hf++)
#pragma unroll
        for (int j = 0; j < 4; j++) {
          float p = exp2f(st[hf][mi][j] - mrun[mi]);
          st[hf][mi][j] = p;
          ps += p;
        }
      ps += __shfl_xor(ps, 16, 64);
      ps += __shfl_xor(ps, 32, 64);
      lrun[mi] += ps;
    }

    // pack P^T fragment (e = hf*4+j), one half8 per mi
    half8 pa[2];
#pragma unroll
    for (int mi = 0; mi < 2; mi++) {
      union { half8 v; _Float16 e[8]; } pu;
#pragma unroll
      for (int hf = 0; hf < 2; hf++)
#pragma unroll
        for (int j = 0; j < 4; j++)
          pu.e[hf * 4 + j] = (_Float16)st[hf][mi][j];
      pa[mi] = pu.v;
    }

    // PV (swapped): A = V^T fragments (linear ds_read), B = P^T
    __builtin_amdgcn_s_setprio(1);
#pragma unroll
    for (int nf = 0; nf < 8; nf++) {
      half8 va = *(const half8*)(lb + 4096 + nf * 512 + lane * 8);
      accO[0][nf] = __builtin_amdgcn_mfma_f32_16x16x32_f16(va, pa[0], accO[0][nf], 0, 0, 0);
      accO[1][nf] = __builtin_amdgcn_mfma_f32_16x16x32_f16(va, pa[1], accO[1][nf], 0, 0, 0);
    }
    __builtin_amdgcn_s_setprio(0);
  }

  // write normalized partials: A = accO/l (f16), m' = m + log2(l)
  const int pidx = h * 80 + cidx(qb) + chunk;
  u16* pob = po + (size_t)pidx * 16384;
#pragma unroll
  for (int mi = 0; mi < 2; mi++) {
    float inv = 1.0f / lrun[mi];
    int row = wid * 32 + mi * 16 + c16;
#pragma unroll
    for (int nf = 0; nf < 8; nf++) {
      u32 p0 = (u32)f2h(accO[mi][nf][0] * inv) | ((u32)f2h(accO[mi][nf][1] * inv) << 16);
      u32 p1 = (u32)f2h(accO[mi][nf][2] * inv) | ((u32)f2h(accO[mi][nf][3] * inv) << 16);
      *(uint2*)&pob[row * 128 + nf * 16 + rg * 4] = make_uint2(p0, p1);
    }
    if (rg == 0)
      ml[(size_t)pidx * 128 + row] = mrun[mi] + log2f(lrun[mi]);
  }
}

// ---------------- combine split-KV partials -> attn (f16) ----------------
__global__ __launch_bounds__(256) void k_attn_combine(
    const u16* __restrict__ po, const float* __restrict__ ml, u16* __restrict__ attn) {
  const int qb = blockIdx.x, h = blockIdx.y;
  const int nc = (qb < 8) ? 1 : (qb < 16) ? 2 : (qb < 24) ? 3 : 4;
  const int base = h * 80 + cidx(qb);
  const int tid = threadIdx.x;
  const int r = tid >> 1, h64 = (tid & 1) * 64;
  float mp[4], M = -1e30f;
#pragma unroll
  for (int ci = 0; ci < 4; ci++) {
    mp[ci] = (ci < nc) ? ml[(size_t)(base + ci) * 128 + r] : -1e30f;
    M = fmaxf(M, mp[ci]);
  }
  float w[4], Ws = 0.f;
#pragma unroll
  for (int ci = 0; ci < 4; ci++) { w[ci] = exp2f(mp[ci] - M); Ws += (ci < nc) ? w[ci] : 0.f; }
  float inv = 1.0f / Ws;
  for (int d = 0; d < 64; d += 4) {
    float a[4] = {0.f, 0.f, 0.f, 0.f};
#pragma unroll
    for (int ci = 0; ci < 4; ci++) {
      if (ci < nc) {
        uint2 u = *(const uint2*)&po[(size_t)(base + ci) * 16384 + r * 128 + h64 + d];
        a[0] += w[ci] * h2f((u16)(u.x & 0xffff));
        a[1] += w[ci] * h2f((u16)(u.x >> 16));
        a[2] += w[ci] * h2f((u16)(u.y & 0xffff));
        a[3] += w[ci] * h2f((u16)(u.y >> 16));
      }
    }
    u32 p0 = (u32)f2h(a[0] * inv) | ((u32)f2h(a[1] * inv) << 16);
    u32 p1 = (u32)f2h(a[2] * inv) | ((u32)f2h(a[3] * inv) << 16);
    *(uint2*)&attn[(size_t)(qb * 128 + r) * DIMM + h * 128 + h64 + d] = make_uint2(p0, p1);
  }
}

// ---------------- out = attn @ wo (f16 GEMM, fp32 out, XCD-swizzled) ----------------
__global__ __launch_bounds__(256) void k_gemm_out(
    const u16* __restrict__ attn, const u16* __restrict__ wot, float* __restrict__ out) {
  __shared__ u16 lds[2 * 128 * 64];  // A | B, 32KB
  const int tid = threadIdx.x;
  const int lane = tid & 63, wid = tid >> 6;
  const int rg = lane >> 4, c16 = lane & 15;
  const int bid0 = blockIdx.y * 16 + blockIdx.x;           // 512 blocks
  const int swz = (bid0 & 7) * 64 + (bid0 >> 3);
  const int m0 = (swz >> 4) * 128, n0 = (swz & 15) * 128;
  const int wm = wid >> 1, wn = wid & 1;
  const u16* gsrc = (wid < 2) ? attn + (size_t)m0 * 2048 : wot + (size_t)n0 * 2048;
  const int sr = lane >> 3, scn = lane & 7;

  f32x4 acc[4][4];
#pragma unroll
  for (int a = 0; a < 4; a++)
#pragma unroll
    for (int b = 0; b < 4; b++) acc[a][b] = (f32x4){0.f, 0.f, 0.f, 0.f};

  for (int k0 = 0; k0 < 2048; k0 += 64) {
#pragma unroll
    for (int i = 0; i < 8; i++) {
      int slot = wid * 8 + i;
      int s2 = slot & 15;
      int r = s2 * 8 + sr;
      int cs = (scn ^ (r & 7)) * 8;
      gll16(gsrc + (size_t)r * 2048 + k0 + cs, lds + slot * 512);
    }
    __syncthreads();
#pragma unroll
    for (int kk = 0; kk < 2; kk++) {
      half8 a[4], b[4];
      int ch = kk * 4 + rg;
#pragma unroll
      for (int mf = 0; mf < 4; mf++) {
        int m = wm * 64 + mf * 16 + c16;
        a[mf] = *(const half8*)(lds + m * 64 + ((ch ^ (m & 7)) * 8));
      }
#pragma unroll
      for (int nf = 0; nf < 4; nf++) {
        int n = wn * 64 + nf * 16 + c16;
        b[nf] = *(const half8*)(lds + 8192 + n * 64 + ((ch ^ (n & 7)) * 8));
      }
#pragma unroll
      for (int mf = 0; mf < 4; mf++)
#pragma unroll
        for (int nf = 0; nf < 4; nf++)
          acc[mf][nf] = __builtin_amdgcn_mfma_f32_16x16x32_f16(a[mf], b[nf], acc[mf][nf], 0, 0, 0);
    }
    __syncthreads();
  }
#pragma unroll
  for (int mf = 0; mf < 4; mf++)
#pragma unroll
    for (int nf = 0; nf < 4; nf++)
#pragma unroll
      for (int j = 0; j < 4; j++) {
        int m = m0 + wm * 64 + mf * 16 + rg * 4 + j;
        int n = n0 + wn * 64 + nf * 16 + c16;
        out[(size_t)m * DIMM + n] = acc[mf][nf][j];
      }
}

extern "C" void kernel_launch(void* const* d_in, const int* in_sizes, int n_in,
                              void* d_out, int out_size, void* d_ws, size_t ws_size,
                              hipStream_t stream) {
  (void)in_sizes; (void)n_in; (void)out_size; (void)ws_size;
  const float* x  = (const float*)d_in[0];
  const float* wq = (const float*)d_in[1];
  const float* wk = (const float*)d_in[2];
  const float* wv = (const float*)d_in[3];
  const float* wo = (const float*)d_in[4];
  float* out = (float*)d_out;

  char* ws = (char*)d_ws;
  const size_t MB = 1024 * 1024;
  // Region A (128MB): xh|xl|wth|wtl|qkv during projection; aliased by po|ml for split-KV
  char* A = ws;
  u16*   xh  = (u16*)(A);
  u16*   xl  = (u16*)(A + 16 * MB);
  u16*   wth = (u16*)(A + 32 * MB);
  u16*   wtl = (u16*)(A + 48 * MB);
  float* qkv = (float*)(A + 64 * MB);
  u16*   po  = (u16*)(A);              // 40MB (1280 x 128 x 128 f16), overlays dead buffers
  float* ml  = (float*)(A + 48 * MB);  // 0.64MB, overlays dead wtl
  // Region B (persistent)
  char* B = ws + 128 * MB;
  size_t off = 0;
  auto alloc = [&](size_t b) { char* p = B + off; off += (b + 255) & ~(size_t)255; return p; };
  u16*   wot  = (u16*)alloc((size_t)DIMM * DIMM * 2);
  float* cosb = (float*)alloc((size_t)SQ * 64 * 4);
  float* sinb = (float*)alloc((size_t)SQ * 64 * 4);
  u16*   qf   = (u16*)alloc((size_t)16 * SQ * 128 * 2);
  u16*   kf2  = (u16*)alloc((size_t)8 * SQ * 128 * 2);
  u16*   vt2  = (u16*)alloc((size_t)8 * 128 * SQ * 2);
  float* bm   = (float*)alloc((size_t)8 * 32 * 128 * 4);
  unsigned char* sel = (unsigned char*)alloc((size_t)16 * SQ);
  u16*   attn = (u16*)alloc((size_t)SQ * DIMM * 2);

  k_tables<<<SQ * 64 / 256, 256, 0, stream>>>(cosb, sinb);
  k_split_x<<<(SQ * DIMM) / (256 * 4), 256, 0, stream>>>(x, xh, xl);
  k_trans_split<<<dim3(32, 32), 256, 0, stream>>>(wq, 2048, wth, wtl, 0);
  k_trans_split<<<dim3(16, 32), 256, 0, stream>>>(wk, 1024, wth, wtl, 2048);
  k_trans_split<<<dim3(16, 32), 256, 0, stream>>>(wv, 1024, wth, wtl, 3072);
  k_trans_f16<<<dim3(32, 32), 256, 0, stream>>>(wo, 2048, wot);
  k_gemm_qkv<<<dim3(32, 32), 256, 0, stream>>>(xh, xl, wth, wtl, qkv);
  k_rope_qk<<<(SQ * 24 * 64) / 256, 256, 0, stream>>>(qkv, cosb, sinb, qf, kf2);
  k_vt2<<<512, 256, 0, stream>>>(qkv, vt2);
  k_bm<<<256, 64, 0, stream>>>(qkv, cosb, sinb, bm);
  k_gate<<<16 * 48, 64, 0, stream>>>(qkv, cosb, sinb, bm, sel);
  // qkv (and xh/xl/wth/wtl) are dead past this point -> po/ml alias them
  k_attn_chunk<<<1280, 256, 0, stream>>>(qf, kf2, vt2, sel, po, ml);
  k_attn_combine<<<dim3(32, 16), 256, 0, stream>>>(po, ml, attn);
  k_gemm_out<<<dim3(16, 32), 256, 0, stream>>>(attn, wot, out);
}